// Round 6
// baseline (363.516 us; speedup 1.0000x reference)
//
#include <hip/hip_runtime.h>
#include <math.h>

#define NN 50000
#define DD 128
#define HH 128
#define L1 64
#define L2 32
#define OO 10

// ---- bf16 helpers (manual: RNE pack) ----
__device__ __forceinline__ float bf2f_lo(unsigned u) { return __uint_as_float(u << 16); }
__device__ __forceinline__ float bf2f_hi(unsigned u) { return __uint_as_float(u & 0xffff0000u); }
__device__ __forceinline__ unsigned short f2bf(float f) {
    unsigned u = __float_as_uint(f);
    return (unsigned short)((u + 0x7fffu + ((u >> 16) & 1u)) >> 16);
}
__device__ __forceinline__ float gelu_f(float v) {
    return 0.5f * v * (1.f + erff(v * 0.70710678118654752f));
}

// ---------------- K1: support = x @ W (x in LDS, W via L1/L2) + fused histogram
// 32 KB LDS only -> 4 blocks/CU (16 waves/CU), raising VALUBusy.
__global__ __launch_bounds__(256, 4) void k_support(
    const float* __restrict__ x, const float* __restrict__ W,
    unsigned short* __restrict__ supb, int rows,
    const int* __restrict__ ei, int* __restrict__ counts, int E)
{
    __shared__ float xs[64][DD];   // 32 KB
    const int tid = threadIdx.x;
    const int row0 = blockIdx.x * 64;

    for (int u = tid * 4; u < 64 * DD; u += 256 * 4) {
        const int r = u >> 7, c = u & 127;
        float4 v = make_float4(0.f, 0.f, 0.f, 0.f);
        if (row0 + r < rows) v = *(const float4*)(x + (size_t)(row0 + r) * DD + c);
        *(float4*)(&xs[r][c]) = v;
    }

    // fused dst-histogram (independent work; atomics hide under the GEMM)
    {
        const int chunk = (E + gridDim.x - 1) / gridDim.x;
        const int e0 = blockIdx.x * chunk;
        const int e1 = min(e0 + chunk, E);
        for (int e = e0 + tid; e < e1; e += 256)
            atomicAdd(&counts[ei[(size_t)E + e]], 1);
    }

    const int cg = tid & 31;   // col group: cols cg*4..+3
    const int rg = tid >> 5;   // 0..7
    float4 acc[8];
    #pragma unroll
    for (int i = 0; i < 8; ++i) acc[i] = make_float4(0.f, 0.f, 0.f, 0.f);
    __syncthreads();

    const float* wp = W + cg * 4;
    #pragma unroll 2
    for (int k = 0; k < DD; k += 4) {
        float4 wv[4];
        #pragma unroll
        for (int jj = 0; jj < 4; ++jj) wv[jj] = *(const float4*)(wp + (size_t)(k + jj) * HH);
        #pragma unroll
        for (int q = 0; q < 2; ++q) {
            #pragma unroll
            for (int i = 0; i < 4; ++i) {
                const float4 xv = *(const float4*)(&xs[q * 32 + rg * 4 + i][k]);
                float4* a = &acc[q * 4 + i];
                a->x = fmaf(xv.x, wv[0].x, fmaf(xv.y, wv[1].x, fmaf(xv.z, wv[2].x, fmaf(xv.w, wv[3].x, a->x))));
                a->y = fmaf(xv.x, wv[0].y, fmaf(xv.y, wv[1].y, fmaf(xv.z, wv[2].y, fmaf(xv.w, wv[3].y, a->y))));
                a->z = fmaf(xv.x, wv[0].z, fmaf(xv.y, wv[1].z, fmaf(xv.z, wv[2].z, fmaf(xv.w, wv[3].z, a->z))));
                a->w = fmaf(xv.x, wv[0].w, fmaf(xv.y, wv[1].w, fmaf(xv.z, wv[2].w, fmaf(xv.w, wv[3].w, a->w))));
            }
        }
    }

    #pragma unroll
    for (int q = 0; q < 2; ++q)
        #pragma unroll
        for (int i = 0; i < 4; ++i) {
            const int r = row0 + q * 32 + rg * 4 + i;
            if (r < rows) {
                const float4 a = acc[q * 4 + i];
                ushort4 o;
                o.x = f2bf(a.x); o.y = f2bf(a.y); o.z = f2bf(a.z); o.w = f2bf(a.w);
                *(ushort4*)(supb + (size_t)r * HH + cg * 4) = o;
            }
        }
}

// ---------------- multi-block scan, stage 1 ----------------
__global__ __launch_bounds__(1024) void k_scan1(
    const int* __restrict__ counts, int* __restrict__ offsets,
    int* __restrict__ blksum, int n)
{
    __shared__ int wsum[16], woff[16];
    const int tid = threadIdx.x, lane = tid & 63, wv = tid >> 6;
    const int i = blockIdx.x * 1024 + tid;
    int v = (i < n) ? counts[i] : 0;
    int x = v;
    #pragma unroll
    for (int d = 1; d < 64; d <<= 1) { int t = __shfl_up(x, d); if (lane >= d) x += t; }
    if (lane == 63) wsum[wv] = x;
    __syncthreads();
    if (wv == 0 && lane < 16) {
        int y = wsum[lane];
        #pragma unroll
        for (int d = 1; d < 16; d <<= 1) { int t = __shfl_up(y, d); if (lane >= d) y += t; }
        woff[lane] = y - wsum[lane];
        if (lane == 15) blksum[blockIdx.x] = y;
    }
    __syncthreads();
    if (i < n) offsets[i] = woff[wv] + (x - v);
}

// ---------------- multi-block scan, stage 2 ----------------
__global__ __launch_bounds__(1024) void k_scan2(
    int* __restrict__ offsets, const int* __restrict__ blksum, int nblk, int n)
{
    __shared__ int base_sh, tot_sh;
    const int tid = threadIdx.x, lane = tid & 63, wv = tid >> 6;
    if (wv == 0) {
        int v = (lane < nblk) ? blksum[lane] : 0;
        int x = v;
        #pragma unroll
        for (int d = 1; d < 64; d <<= 1) { int t = __shfl_up(x, d); if (lane >= d) x += t; }
        int incl = __shfl(x, blockIdx.x);
        int own  = __shfl(v, blockIdx.x);
        int tot  = __shfl(x, nblk - 1);
        if (lane == 0) { base_sh = incl - own; tot_sh = tot; }
    }
    __syncthreads();
    const int i = blockIdx.x * 1024 + tid;
    if (i < n) offsets[i] += base_sh;
    if (blockIdx.x == nblk - 1 && tid == 0) offsets[n] = tot_sh;
}

// ---------------- CSR build: bucket src indices by dst ----------------
__global__ __launch_bounds__(256) void k_bucket(
    const int* __restrict__ ei, const int* __restrict__ offsets,
    int* __restrict__ cursor, int* __restrict__ ss, int E)
{
    int e = blockIdx.x * 256 + threadIdx.x;
    if (e < E) {
        int d = ei[E + e];
        int pos = offsets[d] + atomicAdd(&cursor[d], 1);
        ss[pos] = ei[e];
    }
}

// ---------------- Fused gather-aggregate + GELU + MLP + column sums ----------
// Block = 32 dsts x 2 batches = 64 MLP rows, 512 threads (8 waves).
// Gather phase: wave w handles 4 dsts; lanes 0-31 batch0, 32-63 batch1;
// agg never touches global — gelu(agg+b0) goes straight into LDS.
__global__ __launch_bounds__(512) void k_aggmlp(
    const unsigned short* __restrict__ supb, const int* __restrict__ offsets,
    const int* __restrict__ ss, const float* __restrict__ b0v,
    const float* __restrict__ W1, const float* __restrict__ b1v,
    const float* __restrict__ W2, const float* __restrict__ b2v,
    float* __restrict__ partials, int nn)
{
    __shared__ float w1s[HH][L1];     // 32 KB
    __shared__ float w2s[L1][L2];     // 8 KB
    __shared__ float hs[64 * 136];    // 34 KB; reused for h1 (stride 68), h2 (stride 36)
    __shared__ float b0s[DD], b1s[L1], b2s[L2];
    __shared__ float oacc[64];

    const int tid = threadIdx.x;
    const int d0 = blockIdx.x * 32;

    for (int u = tid * 4; u < HH * L1; u += 2048)
        *(float4*)(&w1s[u >> 6][u & 63]) = *(const float4*)(W1 + u);
    for (int u = tid * 4; u < L1 * L2; u += 2048)
        *(float4*)(&w2s[u >> 5][u & 31]) = *(const float4*)(W2 + u);
    if (tid < DD) b0s[tid] = b0v[tid];
    if (tid < L1) b1s[tid] = b1v[tid];
    if (tid < L2) b2s[tid] = b2v[tid];
    if (tid < 64) oacc[tid] = 0.f;
    __syncthreads();

    // ---- gather phase ----
    {
        const int lane = tid & 63;
        const int wv = tid >> 6;          // 0..7
        const int b = lane >> 5;          // batch
        const int f = lane & 31;          // 4-bf16 group within row
        const unsigned short* sp = supb + (size_t)b * nn * HH + f * 4;
        #pragma unroll
        for (int i4 = 0; i4 < 4; ++i4) {
            const int dl = wv * 4 + i4;   // local dst 0..31
            const int d = d0 + dl;
            float4 a = make_float4(0.f, 0.f, 0.f, 0.f);
            float4 a2 = make_float4(0.f, 0.f, 0.f, 0.f);
            if (d < nn) {
                const int s0 = offsets[d], s1 = offsets[d + 1];
                int i = s0;
                for (; i + 2 <= s1; i += 2) {
                    const int sA = ss[i], sB = ss[i + 1];
                    const uint2 rA = *(const uint2*)(sp + (size_t)sA * HH);
                    const uint2 rB = *(const uint2*)(sp + (size_t)sB * HH);
                    a.x  += bf2f_lo(rA.x); a.y  += bf2f_hi(rA.x); a.z  += bf2f_lo(rA.y); a.w  += bf2f_hi(rA.y);
                    a2.x += bf2f_lo(rB.x); a2.y += bf2f_hi(rB.x); a2.z += bf2f_lo(rB.y); a2.w += bf2f_hi(rB.y);
                }
                if (i < s1) {
                    const uint2 r = *(const uint2*)(sp + (size_t)ss[i] * HH);
                    a.x += bf2f_lo(r.x); a.y += bf2f_hi(r.x); a.z += bf2f_lo(r.y); a.w += bf2f_hi(r.y);
                }
            }
            const float4 bb = *(const float4*)(&b0s[f * 4]);
            float4 g;
            g.x = gelu_f(a.x + a2.x + bb.x);
            g.y = gelu_f(a.y + a2.y + bb.y);
            g.z = gelu_f(a.z + a2.z + bb.z);
            g.w = gelu_f(a.w + a2.w + bb.w);
            *(float4*)(&hs[(b * 32 + dl) * 136 + f * 4]) = g;
        }
    }
    __syncthreads();

    // ---- layer1: thread = 2 rows x 4 cols (64 rows x 64 cols) ----
    const int cg = tid & 15;
    const int rg = tid >> 4;     // 0..31
    float4 acc0 = *(const float4*)(&b1s[cg * 4]);
    float4 acc1 = acc0;
    #pragma unroll 4
    for (int j = 0; j < HH; j += 4) {
        float4 wv[4];
        #pragma unroll
        for (int jj = 0; jj < 4; ++jj) wv[jj] = *(const float4*)(&w1s[j + jj][cg * 4]);
        const float4 h0 = *(const float4*)(&hs[(rg * 2 + 0) * 136 + j]);
        const float4 h1 = *(const float4*)(&hs[(rg * 2 + 1) * 136 + j]);
        acc0.x = fmaf(h0.x, wv[0].x, fmaf(h0.y, wv[1].x, fmaf(h0.z, wv[2].x, fmaf(h0.w, wv[3].x, acc0.x))));
        acc0.y = fmaf(h0.x, wv[0].y, fmaf(h0.y, wv[1].y, fmaf(h0.z, wv[2].y, fmaf(h0.w, wv[3].y, acc0.y))));
        acc0.z = fmaf(h0.x, wv[0].z, fmaf(h0.y, wv[1].z, fmaf(h0.z, wv[2].z, fmaf(h0.w, wv[3].z, acc0.z))));
        acc0.w = fmaf(h0.x, wv[0].w, fmaf(h0.y, wv[1].w, fmaf(h0.z, wv[2].w, fmaf(h0.w, wv[3].w, acc0.w))));
        acc1.x = fmaf(h1.x, wv[0].x, fmaf(h1.y, wv[1].x, fmaf(h1.z, wv[2].x, fmaf(h1.w, wv[3].x, acc1.x))));
        acc1.y = fmaf(h1.x, wv[0].y, fmaf(h1.y, wv[1].y, fmaf(h1.z, wv[2].y, fmaf(h1.w, wv[3].y, acc1.y))));
        acc1.z = fmaf(h1.x, wv[0].z, fmaf(h1.y, wv[1].z, fmaf(h1.z, wv[2].z, fmaf(h1.w, wv[3].z, acc1.z))));
        acc1.w = fmaf(h1.x, wv[0].w, fmaf(h1.y, wv[1].w, fmaf(h1.z, wv[2].w, fmaf(h1.w, wv[3].w, acc1.w))));
    }
    acc0.x = fmaxf(acc0.x, 0.f); acc0.y = fmaxf(acc0.y, 0.f);
    acc0.z = fmaxf(acc0.z, 0.f); acc0.w = fmaxf(acc0.w, 0.f);
    acc1.x = fmaxf(acc1.x, 0.f); acc1.y = fmaxf(acc1.y, 0.f);
    acc1.z = fmaxf(acc1.z, 0.f); acc1.w = fmaxf(acc1.w, 0.f);
    __syncthreads();                       // hs reads done
    float* h1p = hs;                       // [64][68]
    *(float4*)(&h1p[(rg * 2 + 0) * 68 + cg * 4]) = acc0;
    *(float4*)(&h1p[(rg * 2 + 1) * 68 + cg * 4]) = acc1;
    __syncthreads();

    // ---- layer2: thread = 1 row x 4 cols (64 rows x 32 cols) ----
    float* h2p = hs + 5120;                // [64][36]
    {
        const int cg2 = tid & 7;
        const int r2 = tid >> 3;           // 0..63
        float4 a = *(const float4*)(&b2s[cg2 * 4]);
        #pragma unroll 4
        for (int j = 0; j < L1; j += 4) {
            float4 wv[4];
            #pragma unroll
            for (int jj = 0; jj < 4; ++jj) wv[jj] = *(const float4*)(&w2s[j + jj][cg2 * 4]);
            const float4 hv = *(const float4*)(&h1p[r2 * 68 + j]);
            a.x = fmaf(hv.x, wv[0].x, fmaf(hv.y, wv[1].x, fmaf(hv.z, wv[2].x, fmaf(hv.w, wv[3].x, a.x))));
            a.y = fmaf(hv.x, wv[0].y, fmaf(hv.y, wv[1].y, fmaf(hv.z, wv[2].y, fmaf(hv.w, wv[3].y, a.y))));
            a.z = fmaf(hv.x, wv[0].z, fmaf(hv.y, wv[1].z, fmaf(hv.z, wv[2].z, fmaf(hv.w, wv[3].z, a.z))));
            a.w = fmaf(hv.x, wv[0].w, fmaf(hv.y, wv[1].w, fmaf(hv.z, wv[2].w, fmaf(hv.w, wv[3].w, a.w))));
        }
        a.x = fmaxf(a.x, 0.f); a.y = fmaxf(a.y, 0.f);
        a.z = fmaxf(a.z, 0.f); a.w = fmaxf(a.w, 0.f);
        __syncthreads();                   // h1p reads done
        *(float4*)(&h2p[r2 * 36 + cg2 * 4]) = a;
    }
    __syncthreads();

    // ---- column sums (masked by dst validity) -> oacc -> partials ----
    {
        const int c = tid & 31;
        const int g = tid >> 5;            // 0..15, 4 rows each
        float p0 = 0.f, p1 = 0.f;
        #pragma unroll
        for (int i = 0; i < 4; ++i) {
            const int r = g * 4 + i;
            if (d0 + (r & 31) < nn) {
                const float v = h2p[r * 36 + c];
                if (r >= 32) p1 += v; else p0 += v;
            }
        }
        if (p0 != 0.f) atomicAdd(&oacc[c], p0);
        if (p1 != 0.f) atomicAdd(&oacc[32 + c], p1);
    }
    __syncthreads();
    if (tid < 64) partials[(size_t)blockIdx.x * 64 + tid] = oacc[tid];
}

// ---------------- Fallback path kernels (ws too small for CSR) ----------------
__global__ __launch_bounds__(256) void k_scatter(
    const int* __restrict__ ei, const unsigned short* __restrict__ supb,
    float* __restrict__ aggf, int E, int B)
{
    const int tid = threadIdx.x;
    const int eg = tid >> 5;
    const int t4 = (tid & 31) << 2;
    const int e = blockIdx.x * 8 + eg;
    if (e >= E) return;
    const int src = ei[e];
    const int dst = ei[E + e];
    for (int b = 0; b < B; ++b) {
        const uint2 r = *(const uint2*)(supb + ((size_t)b * NN + src) * HH + t4);
        float* ap = aggf + ((size_t)b * NN + dst) * HH + t4;
        unsafeAtomicAdd(ap + 0, bf2f_lo(r.x));
        unsafeAtomicAdd(ap + 1, bf2f_hi(r.x));
        unsafeAtomicAdd(ap + 2, bf2f_lo(r.y));
        unsafeAtomicAdd(ap + 3, bf2f_hi(r.y));
    }
}

// Fallback MLP reading agg (fp32) from global.
__global__ __launch_bounds__(512) void k_mlp_g(
    const float* __restrict__ aggf, const float* __restrict__ b0v,
    const float* __restrict__ W1, const float* __restrict__ b1v,
    const float* __restrict__ W2, const float* __restrict__ b2v,
    float* __restrict__ partials, int rows)
{
    __shared__ float w1s[HH][L1];
    __shared__ float w2s[L1][L2];
    __shared__ float hs[64 * 136];
    __shared__ float b0s[DD], b1s[L1], b2s[L2];
    __shared__ float oacc[64];

    const int tid = threadIdx.x;
    const int row0 = blockIdx.x * 64;

    for (int u = tid * 4; u < HH * L1; u += 2048)
        *(float4*)(&w1s[u >> 6][u & 63]) = *(const float4*)(W1 + u);
    for (int u = tid * 4; u < L1 * L2; u += 2048)
        *(float4*)(&w2s[u >> 5][u & 31]) = *(const float4*)(W2 + u);
    if (tid < DD) b0s[tid] = b0v[tid];
    if (tid < L1) b1s[tid] = b1v[tid];
    if (tid < L2) b2s[tid] = b2v[tid];
    if (tid < 64) oacc[tid] = 0.f;
    __syncthreads();

    for (int u = tid * 4; u < 64 * DD; u += 2048) {
        const int r = u >> 7, c = u & 127;
        float4 g = make_float4(0.f, 0.f, 0.f, 0.f);
        if (row0 + r < rows) {
            const float4 v = *(const float4*)(aggf + (size_t)(row0 + r) * HH + c);
            g.x = gelu_f(v.x + b0s[c + 0]); g.y = gelu_f(v.y + b0s[c + 1]);
            g.z = gelu_f(v.z + b0s[c + 2]); g.w = gelu_f(v.w + b0s[c + 3]);
        }
        *(float4*)(&hs[r * 136 + c]) = g;
    }
    __syncthreads();

    const int cg = tid & 15;
    const int rg = tid >> 4;
    float4 acc0 = *(const float4*)(&b1s[cg * 4]);
    float4 acc1 = acc0;
    for (int j = 0; j < HH; j += 4) {
        float4 wv[4];
        #pragma unroll
        for (int jj = 0; jj < 4; ++jj) wv[jj] = *(const float4*)(&w1s[j + jj][cg * 4]);
        const float4 h0 = *(const float4*)(&hs[(rg * 2 + 0) * 136 + j]);
        const float4 h1 = *(const float4*)(&hs[(rg * 2 + 1) * 136 + j]);
        acc0.x = fmaf(h0.x, wv[0].x, fmaf(h0.y, wv[1].x, fmaf(h0.z, wv[2].x, fmaf(h0.w, wv[3].x, acc0.x))));
        acc0.y = fmaf(h0.x, wv[0].y, fmaf(h0.y, wv[1].y, fmaf(h0.z, wv[2].y, fmaf(h0.w, wv[3].y, acc0.y))));
        acc0.z = fmaf(h0.x, wv[0].z, fmaf(h0.y, wv[1].z, fmaf(h0.z, wv[2].z, fmaf(h0.w, wv[3].z, acc0.z))));
        acc0.w = fmaf(h0.x, wv[0].w, fmaf(h0.y, wv[1].w, fmaf(h0.z, wv[2].w, fmaf(h0.w, wv[3].w, acc0.w))));
        acc1.x = fmaf(h1.x, wv[0].x, fmaf(h1.y, wv[1].x, fmaf(h1.z, wv[2].x, fmaf(h1.w, wv[3].x, acc1.x))));
        acc1.y = fmaf(h1.x, wv[0].y, fmaf(h1.y, wv[1].y, fmaf(h1.z, wv[2].y, fmaf(h1.w, wv[3].y, acc1.y))));
        acc1.z = fmaf(h1.x, wv[0].z, fmaf(h1.y, wv[1].z, fmaf(h1.z, wv[2].z, fmaf(h1.w, wv[3].z, acc1.z))));
        acc1.w = fmaf(h1.x, wv[0].w, fmaf(h1.y, wv[1].w, fmaf(h1.z, wv[2].w, fmaf(h1.w, wv[3].w, acc1.w))));
    }
    acc0.x = fmaxf(acc0.x, 0.f); acc0.y = fmaxf(acc0.y, 0.f);
    acc0.z = fmaxf(acc0.z, 0.f); acc0.w = fmaxf(acc0.w, 0.f);
    acc1.x = fmaxf(acc1.x, 0.f); acc1.y = fmaxf(acc1.y, 0.f);
    acc1.z = fmaxf(acc1.z, 0.f); acc1.w = fmaxf(acc1.w, 0.f);
    __syncthreads();
    float* h1p = hs;
    *(float4*)(&h1p[(rg * 2 + 0) * 68 + cg * 4]) = acc0;
    *(float4*)(&h1p[(rg * 2 + 1) * 68 + cg * 4]) = acc1;
    __syncthreads();

    float* h2p = hs + 5120;
    {
        const int cg2 = tid & 7;
        const int r2 = tid >> 3;
        float4 a = *(const float4*)(&b2s[cg2 * 4]);
        for (int j = 0; j < L1; j += 4) {
            float4 wv[4];
            #pragma unroll
            for (int jj = 0; jj < 4; ++jj) wv[jj] = *(const float4*)(&w2s[j + jj][cg2 * 4]);
            const float4 hv = *(const float4*)(&h1p[r2 * 68 + j]);
            a.x = fmaf(hv.x, wv[0].x, fmaf(hv.y, wv[1].x, fmaf(hv.z, wv[2].x, fmaf(hv.w, wv[3].x, a.x))));
            a.y = fmaf(hv.x, wv[0].y, fmaf(hv.y, wv[1].y, fmaf(hv.z, wv[2].y, fmaf(hv.w, wv[3].y, a.y))));
            a.z = fmaf(hv.x, wv[0].z, fmaf(hv.y, wv[1].z, fmaf(hv.z, wv[2].z, fmaf(hv.w, wv[3].z, a.z))));
            a.w = fmaf(hv.x, wv[0].w, fmaf(hv.y, wv[1].w, fmaf(hv.z, wv[2].w, fmaf(hv.w, wv[3].w, a.w))));
        }
        a.x = fmaxf(a.x, 0.f); a.y = fmaxf(a.y, 0.f);
        a.z = fmaxf(a.z, 0.f); a.w = fmaxf(a.w, 0.f);
        __syncthreads();
        *(float4*)(&h2p[r2 * 36 + cg2 * 4]) = a;
    }
    __syncthreads();

    {
        const int c = tid & 31;
        const int g = tid >> 5;
        float p0 = 0.f, p1 = 0.f;
        #pragma unroll
        for (int i = 0; i < 4; ++i) {
            const int r = g * 4 + i;
            const int grow = row0 + r;
            if (grow < rows) {
                const float v = h2p[r * 36 + c];
                if (grow >= NN) p1 += v; else p0 += v;
            }
        }
        if (p0 != 0.f) atomicAdd(&oacc[c], p0);
        if (p1 != 0.f) atomicAdd(&oacc[32 + c], p1);
    }
    __syncthreads();
    if (tid < 64) partials[(size_t)blockIdx.x * 64 + tid] = oacc[tid];
}

// ---------------- K4a: parallel reduce of partials ----------------
__global__ __launch_bounds__(256) void k_reduce(
    const float* __restrict__ partials, float* __restrict__ accum, int nblk)
{
    __shared__ float lsum[4][64];
    const int t = threadIdx.x & 63;
    const int w = threadIdx.x >> 6;
    float s = 0.f;
    for (int g = blockIdx.x * 4 + w; g < nblk; g += gridDim.x * 4)
        s += partials[(size_t)g * 64 + t];
    lsum[w][t] = s;
    __syncthreads();
    if (threadIdx.x < 64) {
        const float v = lsum[0][t] + lsum[1][t] + lsum[2][t] + lsum[3][t];
        unsafeAtomicAdd(&accum[t], v);
    }
}

// ---------------- K4b: apply layer3 to mean(h2) ----------------
__global__ __launch_bounds__(64) void k_final(
    const float* __restrict__ accum, const float* __restrict__ W3,
    const float* __restrict__ b3v, float* __restrict__ out)
{
    const int tid = threadIdx.x;
    if (tid < 2 * OO) {
        const int b = tid / OO, o = tid % OO;
        float acc = b3v[o];
        const float inv = 1.0f / (float)NN;
        #pragma unroll
        for (int j = 0; j < L2; ++j) acc += (accum[b * 32 + j] * inv) * W3[j * OO + o];
        out[tid] = acc;
    }
}

extern "C" void kernel_launch(void* const* d_in, const int* in_sizes, int n_in,
                              void* d_out, int out_size, void* d_ws, size_t ws_size,
                              hipStream_t stream) {
    const float* x  = (const float*)d_in[0];
    const int*   ei = (const int*)d_in[1];
    const float* W  = (const float*)d_in[2];
    const float* b0 = (const float*)d_in[3];
    const float* W1 = (const float*)d_in[4];
    const float* b1 = (const float*)d_in[5];
    const float* W2 = (const float*)d_in[6];
    const float* b2 = (const float*)d_in[7];
    const float* W3 = (const float*)d_in[8];
    const float* b3 = (const float*)d_in[9];
    float* out = (float*)d_out;

    const int B = in_sizes[0] / (NN * DD);   // 2
    const int E = in_sizes[1] / 2;           // 800000
    const int rows = B * NN;                 // 100000
    const int nblk = (NN + 31) / 32;         // 1563 (also = (rows+63)/64)
    const int nsb = (NN + 1023) / 1024;      // 49 scan blocks

    // workspace layout
    unsigned short* supb = (unsigned short*)d_ws;                    // rows*HH bf16
    float* partials = (float*)(supb + (size_t)rows * HH);            // nblk*64
    float* accum    = partials + (size_t)nblk * 64;                  // 64
    int*   counts   = (int*)(accum + 64);                            // NN
    int*   cursor   = counts + NN;                                   // NN
    int*   offsets  = cursor + NN;                                   // NN+1
    int*   blksum   = offsets + NN + 1;                              // 64
    int*   ss       = blksum + 64;                                   // E
    float* aggf     = (float*)(ss + E);                              // rows*HH (fallback only)
    const size_t need_csr = ((size_t)rows * HH) * sizeof(unsigned short)
                      + ((size_t)nblk * 64 + 64) * sizeof(float)
                      + ((size_t)NN * 3 + 1 + 64 + E) * sizeof(int);
    const size_t need_fb = need_csr + (size_t)rows * HH * sizeof(float);

    if (ws_size >= need_csr && nsb <= 64) {
        hipMemsetAsync(accum, 0, (64 + 2 * (size_t)NN) * sizeof(int), stream);
        k_support<<<dim3((rows + 63) / 64), dim3(256), 0, stream>>>(x, W, supb, rows, ei, counts, E);
        k_scan1<<<dim3(nsb), dim3(1024), 0, stream>>>(counts, offsets, blksum, NN);
        k_scan2<<<dim3(nsb), dim3(1024), 0, stream>>>(offsets, blksum, nsb, NN);
        k_bucket<<<dim3((E + 255) / 256), dim3(256), 0, stream>>>(ei, offsets, cursor, ss, E);
        k_aggmlp<<<dim3(nblk), dim3(512), 0, stream>>>(supb, offsets, ss, b0, W1, b1, W2, b2, partials, NN);
    } else if (ws_size >= need_fb) {
        hipMemsetAsync(accum, 0, 64 * sizeof(float), stream);
        hipMemsetAsync(aggf, 0, (size_t)rows * HH * sizeof(float), stream);
        k_support<<<dim3((rows + 63) / 64), dim3(256), 0, stream>>>(x, W, supb, rows, ei, counts, 0);
        k_scatter<<<dim3((E + 7) / 8), dim3(256), 0, stream>>>(ei, supb, aggf, E, B);
        k_mlp_g<<<dim3(nblk), dim3(512), 0, stream>>>(aggf, b0, W1, b1, W2, b2, partials, rows);
    }

    k_reduce<<<dim3(64), dim3(256), 0, stream>>>(partials, accum, nblk);
    k_final<<<dim3(1), dim3(64), 0, stream>>>(accum, W3, b3, out);
}

// Round 7
// 314.790 us; speedup vs baseline: 1.1548x; 1.1548x over previous
//
#include <hip/hip_runtime.h>
#include <math.h>

#define NN 50000
#define DD 128
#define HH 128
#define L1 64
#define L2 32
#define OO 10

// ---- bf16 helpers (manual: RNE pack) ----
__device__ __forceinline__ float bf2f_lo(unsigned u) { return __uint_as_float(u << 16); }
__device__ __forceinline__ float bf2f_hi(unsigned u) { return __uint_as_float(u & 0xffff0000u); }
__device__ __forceinline__ unsigned short f2bf(float f) {
    unsigned u = __float_as_uint(f);
    return (unsigned short)((u + 0x7fffu + ((u >> 16) & 1u)) >> 16);
}
__device__ __forceinline__ float gelu_f(float v) {
    return 0.5f * v * (1.f + erff(v * 0.70710678118654752f));
}

// ---------------- K1: support = x @ W (x in LDS, W via L1/L2) + fused histogram
// 32 KB LDS -> 4 blocks/CU. Output layout INTERLEAVED: storage row = node*2+batch,
// so both batches of one node are a contiguous 512 B bf16 block (gather-friendly).
__global__ __launch_bounds__(256, 4) void k_support(
    const float* __restrict__ x, const float* __restrict__ W,
    unsigned short* __restrict__ supb, int rows,
    const int* __restrict__ ei, int* __restrict__ counts, int E)
{
    __shared__ float xs[64][DD];   // 32 KB
    const int tid = threadIdx.x;
    const int row0 = blockIdx.x * 64;

    for (int u = tid * 4; u < 64 * DD; u += 256 * 4) {
        const int r = u >> 7, c = u & 127;
        float4 v = make_float4(0.f, 0.f, 0.f, 0.f);
        if (row0 + r < rows) v = *(const float4*)(x + (size_t)(row0 + r) * DD + c);
        *(float4*)(&xs[r][c]) = v;
    }

    // fused dst-histogram (independent work; atomics hide under the GEMM)
    {
        const int chunk = (E + gridDim.x - 1) / gridDim.x;
        const int e0 = blockIdx.x * chunk;
        const int e1 = min(e0 + chunk, E);
        for (int e = e0 + tid; e < e1; e += 256)
            atomicAdd(&counts[ei[(size_t)E + e]], 1);
    }

    const int cg = tid & 31;   // col group: cols cg*4..+3
    const int rg = tid >> 5;   // 0..7
    float4 acc[8];
    #pragma unroll
    for (int i = 0; i < 8; ++i) acc[i] = make_float4(0.f, 0.f, 0.f, 0.f);
    __syncthreads();

    const float* wp = W + cg * 4;
    #pragma unroll 2
    for (int k = 0; k < DD; k += 4) {
        float4 wv[4];
        #pragma unroll
        for (int jj = 0; jj < 4; ++jj) wv[jj] = *(const float4*)(wp + (size_t)(k + jj) * HH);
        #pragma unroll
        for (int q = 0; q < 2; ++q) {
            #pragma unroll
            for (int i = 0; i < 4; ++i) {
                const float4 xv = *(const float4*)(&xs[q * 32 + rg * 4 + i][k]);
                float4* a = &acc[q * 4 + i];
                a->x = fmaf(xv.x, wv[0].x, fmaf(xv.y, wv[1].x, fmaf(xv.z, wv[2].x, fmaf(xv.w, wv[3].x, a->x))));
                a->y = fmaf(xv.x, wv[0].y, fmaf(xv.y, wv[1].y, fmaf(xv.z, wv[2].y, fmaf(xv.w, wv[3].y, a->y))));
                a->z = fmaf(xv.x, wv[0].z, fmaf(xv.y, wv[1].z, fmaf(xv.z, wv[2].z, fmaf(xv.w, wv[3].z, a->z))));
                a->w = fmaf(xv.x, wv[0].w, fmaf(xv.y, wv[1].w, fmaf(xv.z, wv[2].w, fmaf(xv.w, wv[3].w, a->w))));
            }
        }
    }

    #pragma unroll
    for (int q = 0; q < 2; ++q)
        #pragma unroll
        for (int i = 0; i < 4; ++i) {
            const int r = row0 + q * 32 + rg * 4 + i;   // global row = b*NN + n
            if (r < rows) {
                const int b = (r >= NN) ? 1 : 0;
                const int n = r - b * NN;
                const size_t sr = (size_t)n * 2 + b;     // interleaved storage row
                const float4 a = acc[q * 4 + i];
                ushort4 o;
                o.x = f2bf(a.x); o.y = f2bf(a.y); o.z = f2bf(a.z); o.w = f2bf(a.w);
                *(ushort4*)(supb + sr * HH + cg * 4) = o;
            }
        }
}

// ---------------- multi-block scan, stage 1 ----------------
__global__ __launch_bounds__(1024) void k_scan1(
    const int* __restrict__ counts, int* __restrict__ offsets,
    int* __restrict__ blksum, int n)
{
    __shared__ int wsum[16], woff[16];
    const int tid = threadIdx.x, lane = tid & 63, wv = tid >> 6;
    const int i = blockIdx.x * 1024 + tid;
    int v = (i < n) ? counts[i] : 0;
    int x = v;
    #pragma unroll
    for (int d = 1; d < 64; d <<= 1) { int t = __shfl_up(x, d); if (lane >= d) x += t; }
    if (lane == 63) wsum[wv] = x;
    __syncthreads();
    if (wv == 0 && lane < 16) {
        int y = wsum[lane];
        #pragma unroll
        for (int d = 1; d < 16; d <<= 1) { int t = __shfl_up(y, d); if (lane >= d) y += t; }
        woff[lane] = y - wsum[lane];
        if (lane == 15) blksum[blockIdx.x] = y;
    }
    __syncthreads();
    if (i < n) offsets[i] = woff[wv] + (x - v);
}

// ---------------- multi-block scan, stage 2 ----------------
__global__ __launch_bounds__(1024) void k_scan2(
    int* __restrict__ offsets, const int* __restrict__ blksum, int nblk, int n)
{
    __shared__ int base_sh, tot_sh;
    const int tid = threadIdx.x, lane = tid & 63, wv = tid >> 6;
    if (wv == 0) {
        int v = (lane < nblk) ? blksum[lane] : 0;
        int x = v;
        #pragma unroll
        for (int d = 1; d < 64; d <<= 1) { int t = __shfl_up(x, d); if (lane >= d) x += t; }
        int incl = __shfl(x, blockIdx.x);
        int own  = __shfl(v, blockIdx.x);
        int tot  = __shfl(x, nblk - 1);
        if (lane == 0) { base_sh = incl - own; tot_sh = tot; }
    }
    __syncthreads();
    const int i = blockIdx.x * 1024 + tid;
    if (i < n) offsets[i] += base_sh;
    if (blockIdx.x == nblk - 1 && tid == 0) offsets[n] = tot_sh;
}

// ---------------- CSR build: bucket src indices by dst ----------------
__global__ __launch_bounds__(256) void k_bucket(
    const int* __restrict__ ei, const int* __restrict__ offsets,
    int* __restrict__ cursor, int* __restrict__ ss, int E)
{
    int e = blockIdx.x * 256 + threadIdx.x;
    if (e < E) {
        int d = ei[E + e];
        int pos = offsets[d] + atomicAdd(&cursor[d], 1);
        ss[pos] = ei[e];
    }
}

// ---------------- K2: gather-aggregate over interleaved bf16 rows -------------
// One wave per dst; 64 lanes x 8 B = one contiguous 512 B block per edge
// (both batches of the src node). Zero LDS, 20 VGPR -> max occupancy. x4 unroll.
__global__ __launch_bounds__(256) void k_agg(
    const unsigned short* __restrict__ supb, const int* __restrict__ offsets,
    const int* __restrict__ ss, unsigned short* __restrict__ aggb, int nn)
{
    const int tid = threadIdx.x;
    const int lane = tid & 63;
    const int wv = tid >> 6;
    const int d = blockIdx.x * 4 + wv;
    if (d >= nn) return;
    const unsigned short* sp = supb + lane * 4;   // lane's 8 B slot within 512 B node block
    const int s0 = offsets[d], s1 = offsets[d + 1];
    float4 a = make_float4(0.f, 0.f, 0.f, 0.f);
    float4 a2 = make_float4(0.f, 0.f, 0.f, 0.f);
    int i = s0;
    for (; i + 4 <= s1; i += 4) {
        const int sA = ss[i], sB = ss[i + 1], sC = ss[i + 2], sD = ss[i + 3];
        const uint2 rA = *(const uint2*)(sp + (size_t)sA * 256);
        const uint2 rB = *(const uint2*)(sp + (size_t)sB * 256);
        const uint2 rC = *(const uint2*)(sp + (size_t)sC * 256);
        const uint2 rD = *(const uint2*)(sp + (size_t)sD * 256);
        a.x  += bf2f_lo(rA.x); a.y  += bf2f_hi(rA.x); a.z  += bf2f_lo(rA.y); a.w  += bf2f_hi(rA.y);
        a2.x += bf2f_lo(rB.x); a2.y += bf2f_hi(rB.x); a2.z += bf2f_lo(rB.y); a2.w += bf2f_hi(rB.y);
        a.x  += bf2f_lo(rC.x); a.y  += bf2f_hi(rC.x); a.z  += bf2f_lo(rC.y); a.w  += bf2f_hi(rC.y);
        a2.x += bf2f_lo(rD.x); a2.y += bf2f_hi(rD.x); a2.z += bf2f_lo(rD.y); a2.w += bf2f_hi(rD.y);
    }
    for (; i < s1; ++i) {
        const uint2 r = *(const uint2*)(sp + (size_t)ss[i] * 256);
        a.x += bf2f_lo(r.x); a.y += bf2f_hi(r.x); a.z += bf2f_lo(r.y); a.w += bf2f_hi(r.y);
    }
    a.x += a2.x; a.y += a2.y; a.z += a2.z; a.w += a2.w;
    ushort4 o;
    o.x = f2bf(a.x); o.y = f2bf(a.y); o.z = f2bf(a.z); o.w = f2bf(a.w);
    *(ushort4*)(aggb + (size_t)d * 256 + lane * 4) = o;
}

// ---------------- K3: gelu + MLP(128->64->32) + per-block h2 column sums ------
// 64 storage rows/block (= 32 nodes x 2 batches), 512 threads; interleaved aggb
// makes the agg read perfectly linear. hs LDS reused for h1/h2. ~76 KB -> 2/CU.
__global__ __launch_bounds__(512) void k_mlp(
    const unsigned short* __restrict__ aggb, const float* __restrict__ b0v,
    const float* __restrict__ W1, const float* __restrict__ b1v,
    const float* __restrict__ W2, const float* __restrict__ b2v,
    float* __restrict__ partials, int srows)   // srows = 2*nn storage rows
{
    __shared__ float w1s[HH][L1];        // 32 KB
    __shared__ float w2s[L1][L2];        // 8 KB
    __shared__ float hs[64 * 136];       // 34 KB; reused for h1 (stride 68), h2 (stride 36)
    __shared__ float b0s[DD], b1s[L1], b2s[L2];
    __shared__ float oacc[64];

    const int tid = threadIdx.x;
    const int row0 = blockIdx.x * 64;    // storage-row base (even)

    for (int u = tid * 4; u < HH * L1; u += 2048)
        *(float4*)(&w1s[u >> 6][u & 63]) = *(const float4*)(W1 + u);
    for (int u = tid * 4; u < L1 * L2; u += 2048)
        *(float4*)(&w2s[u >> 5][u & 31]) = *(const float4*)(W2 + u);
    if (tid < DD) b0s[tid] = b0v[tid];
    if (tid < L1) b1s[tid] = b1v[tid];
    if (tid < L2) b2s[tid] = b2v[tid];
    if (tid < 64) oacc[tid] = 0.f;
    __syncthreads();

    // gelu(agg_bf16 + b0) -> hs (8 elems/thread/iter; linear global reads)
    for (int u = tid * 8; u < 64 * DD; u += 512 * 8) {
        const int r = u >> 7, c = u & 127;
        float4 g0 = make_float4(0.f, 0.f, 0.f, 0.f);
        float4 g1 = g0;
        if (row0 + r < srows) {
            const uint4 raw = *(const uint4*)(aggb + (size_t)(row0 + r) * HH + c);
            float v[8];
            v[0] = bf2f_lo(raw.x) + b0s[c + 0]; v[1] = bf2f_hi(raw.x) + b0s[c + 1];
            v[2] = bf2f_lo(raw.y) + b0s[c + 2]; v[3] = bf2f_hi(raw.y) + b0s[c + 3];
            v[4] = bf2f_lo(raw.z) + b0s[c + 4]; v[5] = bf2f_hi(raw.z) + b0s[c + 5];
            v[6] = bf2f_lo(raw.w) + b0s[c + 6]; v[7] = bf2f_hi(raw.w) + b0s[c + 7];
            #pragma unroll
            for (int t = 0; t < 8; ++t) v[t] = gelu_f(v[t]);
            g0 = make_float4(v[0], v[1], v[2], v[3]);
            g1 = make_float4(v[4], v[5], v[6], v[7]);
        }
        *(float4*)(&hs[r * 136 + c]) = g0;
        *(float4*)(&hs[r * 136 + c + 4]) = g1;
    }
    __syncthreads();

    // layer1: thread = 2 rows x 4 cols (64 rows x 64 cols)
    const int cg = tid & 15;
    const int rg = tid >> 4;     // 0..31
    float4 acc0 = *(const float4*)(&b1s[cg * 4]);
    float4 acc1 = acc0;
    #pragma unroll 4
    for (int j = 0; j < HH; j += 4) {
        float4 wv[4];
        #pragma unroll
        for (int jj = 0; jj < 4; ++jj) wv[jj] = *(const float4*)(&w1s[j + jj][cg * 4]);
        const float4 h0 = *(const float4*)(&hs[(rg * 2 + 0) * 136 + j]);
        const float4 h1 = *(const float4*)(&hs[(rg * 2 + 1) * 136 + j]);
        acc0.x = fmaf(h0.x, wv[0].x, fmaf(h0.y, wv[1].x, fmaf(h0.z, wv[2].x, fmaf(h0.w, wv[3].x, acc0.x))));
        acc0.y = fmaf(h0.x, wv[0].y, fmaf(h0.y, wv[1].y, fmaf(h0.z, wv[2].y, fmaf(h0.w, wv[3].y, acc0.y))));
        acc0.z = fmaf(h0.x, wv[0].z, fmaf(h0.y, wv[1].z, fmaf(h0.z, wv[2].z, fmaf(h0.w, wv[3].z, acc0.z))));
        acc0.w = fmaf(h0.x, wv[0].w, fmaf(h0.y, wv[1].w, fmaf(h0.z, wv[2].w, fmaf(h0.w, wv[3].w, acc0.w))));
        acc1.x = fmaf(h1.x, wv[0].x, fmaf(h1.y, wv[1].x, fmaf(h1.z, wv[2].x, fmaf(h1.w, wv[3].x, acc1.x))));
        acc1.y = fmaf(h1.x, wv[0].y, fmaf(h1.y, wv[1].y, fmaf(h1.z, wv[2].y, fmaf(h1.w, wv[3].y, acc1.y))));
        acc1.z = fmaf(h1.x, wv[0].z, fmaf(h1.y, wv[1].z, fmaf(h1.z, wv[2].z, fmaf(h1.w, wv[3].z, acc1.z))));
        acc1.w = fmaf(h1.x, wv[0].w, fmaf(h1.y, wv[1].w, fmaf(h1.z, wv[2].w, fmaf(h1.w, wv[3].w, acc1.w))));
    }
    acc0.x = fmaxf(acc0.x, 0.f); acc0.y = fmaxf(acc0.y, 0.f);
    acc0.z = fmaxf(acc0.z, 0.f); acc0.w = fmaxf(acc0.w, 0.f);
    acc1.x = fmaxf(acc1.x, 0.f); acc1.y = fmaxf(acc1.y, 0.f);
    acc1.z = fmaxf(acc1.z, 0.f); acc1.w = fmaxf(acc1.w, 0.f);
    __syncthreads();                       // hs reads done
    float* h1p = hs;                       // [64][68]
    *(float4*)(&h1p[(rg * 2 + 0) * 68 + cg * 4]) = acc0;
    *(float4*)(&h1p[(rg * 2 + 1) * 68 + cg * 4]) = acc1;
    __syncthreads();

    // layer2: thread = 1 row x 4 cols (64 rows x 32 cols)
    float* h2p = hs + 5120;                // [64][36]
    {
        const int cg2 = tid & 7;
        const int r2 = tid >> 3;           // 0..63
        float4 a = *(const float4*)(&b2s[cg2 * 4]);
        #pragma unroll 4
        for (int j = 0; j < L1; j += 4) {
            float4 wv[4];
            #pragma unroll
            for (int jj = 0; jj < 4; ++jj) wv[jj] = *(const float4*)(&w2s[j + jj][cg2 * 4]);
            const float4 hv = *(const float4*)(&h1p[r2 * 68 + j]);
            a.x = fmaf(hv.x, wv[0].x, fmaf(hv.y, wv[1].x, fmaf(hv.z, wv[2].x, fmaf(hv.w, wv[3].x, a.x))));
            a.y = fmaf(hv.x, wv[0].y, fmaf(hv.y, wv[1].y, fmaf(hv.z, wv[2].y, fmaf(hv.w, wv[3].y, a.y))));
            a.z = fmaf(hv.x, wv[0].z, fmaf(hv.y, wv[1].z, fmaf(hv.z, wv[2].z, fmaf(hv.w, wv[3].z, a.z))));
            a.w = fmaf(hv.x, wv[0].w, fmaf(hv.y, wv[1].w, fmaf(hv.z, wv[2].w, fmaf(hv.w, wv[3].w, a.w))));
        }
        a.x = fmaxf(a.x, 0.f); a.y = fmaxf(a.y, 0.f);
        a.z = fmaxf(a.z, 0.f); a.w = fmaxf(a.w, 0.f);
        __syncthreads();                   // h1p reads done
        *(float4*)(&h2p[r2 * 36 + cg2 * 4]) = a;
    }
    __syncthreads();

    // column sums: storage row r -> batch = r&1 -> oacc -> partials
    {
        const int c = tid & 31;
        const int g = tid >> 5;            // 0..15, 4 rows each
        float p0 = 0.f, p1 = 0.f;
        #pragma unroll
        for (int i = 0; i < 4; ++i) {
            const int r = g * 4 + i;
            if (row0 + r < srows) {
                const float v = h2p[r * 36 + c];
                if (r & 1) p1 += v; else p0 += v;
            }
        }
        if (p0 != 0.f) atomicAdd(&oacc[c], p0);
        if (p1 != 0.f) atomicAdd(&oacc[32 + c], p1);
    }
    __syncthreads();
    if (tid < 64) partials[(size_t)blockIdx.x * 64 + tid] = oacc[tid];
}

// ---------------- Fallback path (ws too small for CSR): interleaved layouts ----
__global__ __launch_bounds__(256) void k_scatter(
    const int* __restrict__ ei, const unsigned short* __restrict__ supb,
    float* __restrict__ aggf, int E)
{
    const int tid = threadIdx.x;
    const int eg = tid >> 6;               // 4 edges/block, 64 lanes each
    const int lane = tid & 63;
    const int e = blockIdx.x * 4 + eg;
    if (e >= E) return;
    const int src = ei[e];
    const int dst = ei[E + e];
    const uint2 r = *(const uint2*)(supb + (size_t)src * 256 + lane * 4);
    float* ap = aggf + (size_t)dst * 256 + lane * 4;
    unsafeAtomicAdd(ap + 0, bf2f_lo(r.x));
    unsafeAtomicAdd(ap + 1, bf2f_hi(r.x));
    unsafeAtomicAdd(ap + 2, bf2f_lo(r.y));
    unsafeAtomicAdd(ap + 3, bf2f_hi(r.y));
}

__global__ __launch_bounds__(256) void k_cvt(
    const float* __restrict__ in, unsigned short* __restrict__ outb, int n)
{
    int i = blockIdx.x * 256 + threadIdx.x;
    if (i < n) outb[i] = f2bf(in[i]);
}

// ---------------- K4a: parallel reduce of partials ----------------
__global__ __launch_bounds__(256) void k_reduce(
    const float* __restrict__ partials, float* __restrict__ accum, int nblk)
{
    __shared__ float lsum[4][64];
    const int t = threadIdx.x & 63;
    const int w = threadIdx.x >> 6;
    float s = 0.f;
    for (int g = blockIdx.x * 4 + w; g < nblk; g += gridDim.x * 4)
        s += partials[(size_t)g * 64 + t];
    lsum[w][t] = s;
    __syncthreads();
    if (threadIdx.x < 64) {
        const float v = lsum[0][t] + lsum[1][t] + lsum[2][t] + lsum[3][t];
        unsafeAtomicAdd(&accum[t], v);
    }
}

// ---------------- K4b: apply layer3 to mean(h2) ----------------
__global__ __launch_bounds__(64) void k_final(
    const float* __restrict__ accum, const float* __restrict__ W3,
    const float* __restrict__ b3v, float* __restrict__ out)
{
    const int tid = threadIdx.x;
    if (tid < 2 * OO) {
        const int b = tid / OO, o = tid % OO;
        float acc = b3v[o];
        const float inv = 1.0f / (float)NN;
        #pragma unroll
        for (int j = 0; j < L2; ++j) acc += (accum[b * 32 + j] * inv) * W3[j * OO + o];
        out[tid] = acc;
    }
}

extern "C" void kernel_launch(void* const* d_in, const int* in_sizes, int n_in,
                              void* d_out, int out_size, void* d_ws, size_t ws_size,
                              hipStream_t stream) {
    const float* x  = (const float*)d_in[0];
    const int*   ei = (const int*)d_in[1];
    const float* W  = (const float*)d_in[2];
    const float* b0 = (const float*)d_in[3];
    const float* W1 = (const float*)d_in[4];
    const float* b1 = (const float*)d_in[5];
    const float* W2 = (const float*)d_in[6];
    const float* b2 = (const float*)d_in[7];
    const float* W3 = (const float*)d_in[8];
    const float* b3 = (const float*)d_in[9];
    float* out = (float*)d_out;

    const int E = in_sizes[1] / 2;           // 800000
    const int rows = 2 * NN;                 // 100000 storage rows
    const int nblk = (rows + 63) / 64;       // 1563
    const int nsb = (NN + 1023) / 1024;      // 49 scan blocks

    // workspace layout
    unsigned short* supb = (unsigned short*)d_ws;                    // rows*HH bf16 (interleaved)
    unsigned short* aggb = supb + (size_t)rows * HH;                 // rows*HH bf16 (interleaved)
    float* partials = (float*)(aggb + (size_t)rows * HH);            // nblk*64
    float* accum    = partials + (size_t)nblk * 64;                  // 64
    int*   counts   = (int*)(accum + 64);                            // NN
    int*   cursor   = counts + NN;                                   // NN
    int*   offsets  = cursor + NN;                                   // NN+1
    int*   blksum   = offsets + NN + 1;                              // 64
    int*   ss       = blksum + 64;                                   // E
    float* aggf     = (float*)(ss + E);                              // rows*HH (fallback only)
    const size_t need_csr = ((size_t)rows * HH * 2) * sizeof(unsigned short)
                      + ((size_t)nblk * 64 + 64) * sizeof(float)
                      + ((size_t)NN * 3 + 1 + 64 + E) * sizeof(int);
    const size_t need_fb = need_csr + (size_t)rows * HH * sizeof(float);

    if (ws_size >= need_csr && nsb <= 64) {
        hipMemsetAsync(accum, 0, (64 + 2 * (size_t)NN) * sizeof(int), stream);
        k_support<<<dim3((rows + 63) / 64), dim3(256), 0, stream>>>(x, W, supb, rows, ei, counts, E);
        k_scan1<<<dim3(nsb), dim3(1024), 0, stream>>>(counts, offsets, blksum, NN);
        k_scan2<<<dim3(nsb), dim3(1024), 0, stream>>>(offsets, blksum, nsb, NN);
        k_bucket<<<dim3((E + 255) / 256), dim3(256), 0, stream>>>(ei, offsets, cursor, ss, E);
        k_agg<<<dim3((NN + 3) / 4), dim3(256), 0, stream>>>(supb, offsets, ss, aggb, NN);
        k_mlp<<<dim3(nblk), dim3(512), 0, stream>>>(aggb, b0, W1, b1, W2, b2, partials, rows);
    } else if (ws_size >= need_fb) {
        hipMemsetAsync(accum, 0, 64 * sizeof(float), stream);
        hipMemsetAsync(aggf, 0, (size_t)rows * HH * sizeof(float), stream);
        k_support<<<dim3((rows + 63) / 64), dim3(256), 0, stream>>>(x, W, supb, rows, ei, counts, 0);
        k_scatter<<<dim3((E + 3) / 4), dim3(256), 0, stream>>>(ei, supb, aggf, E);
        k_cvt<<<dim3((rows * HH + 255) / 256), dim3(256), 0, stream>>>(aggf, aggb, rows * HH);
        k_mlp<<<dim3(nblk), dim3(512), 0, stream>>>(aggb, b0, W1, b1, W2, b2, partials, rows);
    }

    k_reduce<<<dim3(64), dim3(256), 0, stream>>>(partials, accum, nblk);
    k_final<<<dim3(1), dim3(64), 0, stream>>>(accum, W3, b3, out);
}

// Round 8
// 310.227 us; speedup vs baseline: 1.1718x; 1.0147x over previous
//
#include <hip/hip_runtime.h>
#include <math.h>

#define NN 50000
#define DD 128
#define HH 128
#define L1 64
#define L2 32
#define OO 10

typedef short v8s __attribute__((ext_vector_type(8)));   // 8 bf16 (4 VGPRs)
typedef float v4f __attribute__((ext_vector_type(4)));   // MFMA accumulator

// ---- bf16 helpers (manual: RNE pack) ----
__device__ __forceinline__ float bf2f_lo(unsigned u) { return __uint_as_float(u << 16); }
__device__ __forceinline__ float bf2f_hi(unsigned u) { return __uint_as_float(u & 0xffff0000u); }
__device__ __forceinline__ unsigned short f2bf(float f) {
    unsigned u = __float_as_uint(f);
    return (unsigned short)((u + 0x7fffu + ((u >> 16) & 1u)) >> 16);
}
__device__ __forceinline__ float gelu_f(float v) {
    return 0.5f * v * (1.f + erff(v * 0.70710678118654752f));
}

// ---------------- K0: one-time W -> W^T bf16, padded to [128][136] ----------------
__global__ __launch_bounds__(256) void k_wprep(
    const float* __restrict__ W, unsigned short* __restrict__ wtb)
{
    int i = blockIdx.x * 256 + threadIdx.x;
    if (i < 128 * 136) {
        int n = i / 136, k = i % 136;
        wtb[i] = (k < DD) ? f2bf(W[k * HH + n]) : (unsigned short)0;
    }
}

// ---------------- K1: support = x @ W via bf16 MFMA + fused dst histogram ------
// 64 rows/block, 4 waves; wave w -> rows w*16..+16, all 128 cols (8 col-tiles).
// LDS: xs 64x136 bf16 (17.4 KB) + wt 128x136 bf16 (34.8 KB) = 52 KB -> 3 blk/CU.
// Output interleaved: storage row = node*2+batch (contiguous 512 B per node pair).
__global__ __launch_bounds__(256) void k_support(
    const float* __restrict__ x, const unsigned short* __restrict__ wtb,
    unsigned short* __restrict__ supb, int rows,
    const int* __restrict__ ei, int* __restrict__ counts, int E)
{
    __shared__ __align__(16) unsigned short xs[64 * 136];
    __shared__ __align__(16) unsigned short wt[128 * 136];
    const int tid = threadIdx.x;
    const int row0 = blockIdx.x * 64;

    // stage W^T (linear, conflict-free copy of pre-padded global buffer)
    for (int u = tid * 4; u < 128 * 136; u += 1024)
        *(uint2*)(&wt[u]) = *(const uint2*)(wtb + u);
    // stage x tile, fp32 -> bf16
    for (int u = tid * 4; u < 64 * DD; u += 1024) {
        const int r = u >> 7, c = u & 127;
        float4 v = make_float4(0.f, 0.f, 0.f, 0.f);
        if (row0 + r < rows) v = *(const float4*)(x + (size_t)(row0 + r) * DD + c);
        ushort4 o;
        o.x = f2bf(v.x); o.y = f2bf(v.y); o.z = f2bf(v.z); o.w = f2bf(v.w);
        *(ushort4*)(&xs[r * 136 + c]) = o;
    }

    // fused dst-histogram (independent; atomics fly under staging/MFMA)
    {
        const int chunk = (E + gridDim.x - 1) / gridDim.x;
        const int e0 = blockIdx.x * chunk;
        const int e1 = min(e0 + chunk, E);
        for (int e = e0 + tid; e < e1; e += 256)
            atomicAdd(&counts[ei[(size_t)E + e]], 1);
    }
    __syncthreads();

    const int lane = tid & 63;
    const int w = tid >> 6;       // wave 0..3
    const int m0 = w * 16;        // wave's row base (block-local)
    const int lm = lane & 15;
    const int q  = lane >> 4;     // 0..3

    v4f acc[8];
    #pragma unroll
    for (int i = 0; i < 8; ++i) acc[i] = (v4f)(0.f);

    #pragma unroll
    for (int ks = 0; ks < 4; ++ks) {
        const int k0 = ks * 32 + q * 8;
        const v8s af = *(const v8s*)(&xs[(m0 + lm) * 136 + k0]);
        #pragma unroll
        for (int ct = 0; ct < 8; ++ct) {
            const v8s bf = *(const v8s*)(&wt[(ct * 16 + lm) * 136 + k0]);
            acc[ct] = __builtin_amdgcn_mfma_f32_16x16x32_bf16(af, bf, acc[ct], 0, 0, 0);
        }
    }

    // C/D: col = lane&15 (+16*ct), row = q*4 + reg  [m89-verified]
    #pragma unroll
    for (int ct = 0; ct < 8; ++ct) {
        const int col = ct * 16 + lm;
        #pragma unroll
        for (int r = 0; r < 4; ++r) {
            const int rowg = row0 + m0 + q * 4 + r;
            if (rowg < rows) {
                const int b = (rowg >= NN) ? 1 : 0;
                const int n = rowg - b * NN;
                supb[((size_t)n * 2 + b) * HH + col] = f2bf(acc[ct][r]);
            }
        }
    }
}

// ---------------- multi-block scan, stage 1 ----------------
__global__ __launch_bounds__(1024) void k_scan1(
    const int* __restrict__ counts, int* __restrict__ offsets,
    int* __restrict__ blksum, int n)
{
    __shared__ int wsum[16], woff[16];
    const int tid = threadIdx.x, lane = tid & 63, wv = tid >> 6;
    const int i = blockIdx.x * 1024 + tid;
    int v = (i < n) ? counts[i] : 0;
    int x = v;
    #pragma unroll
    for (int d = 1; d < 64; d <<= 1) { int t = __shfl_up(x, d); if (lane >= d) x += t; }
    if (lane == 63) wsum[wv] = x;
    __syncthreads();
    if (wv == 0 && lane < 16) {
        int y = wsum[lane];
        #pragma unroll
        for (int d = 1; d < 16; d <<= 1) { int t = __shfl_up(y, d); if (lane >= d) y += t; }
        woff[lane] = y - wsum[lane];
        if (lane == 15) blksum[blockIdx.x] = y;
    }
    __syncthreads();
    if (i < n) offsets[i] = woff[wv] + (x - v);
}

// ---------------- multi-block scan, stage 2 ----------------
__global__ __launch_bounds__(1024) void k_scan2(
    int* __restrict__ offsets, const int* __restrict__ blksum, int nblk, int n)
{
    __shared__ int base_sh, tot_sh;
    const int tid = threadIdx.x, lane = tid & 63, wv = tid >> 6;
    if (wv == 0) {
        int v = (lane < nblk) ? blksum[lane] : 0;
        int x = v;
        #pragma unroll
        for (int d = 1; d < 64; d <<= 1) { int t = __shfl_up(x, d); if (lane >= d) x += t; }
        int incl = __shfl(x, blockIdx.x);
        int own  = __shfl(v, blockIdx.x);
        int tot  = __shfl(x, nblk - 1);
        if (lane == 0) { base_sh = incl - own; tot_sh = tot; }
    }
    __syncthreads();
    const int i = blockIdx.x * 1024 + tid;
    if (i < n) offsets[i] += base_sh;
    if (blockIdx.x == nblk - 1 && tid == 0) offsets[n] = tot_sh;
}

// ---------------- CSR build: bucket src indices by dst ----------------
__global__ __launch_bounds__(256) void k_bucket(
    const int* __restrict__ ei, const int* __restrict__ offsets,
    int* __restrict__ cursor, int* __restrict__ ss, int E)
{
    int e = blockIdx.x * 256 + threadIdx.x;
    if (e < E) {
        int d = ei[E + e];
        int pos = offsets[d] + atomicAdd(&cursor[d], 1);
        ss[pos] = ei[e];
    }
}

// ---------------- K2: gather-aggregate over interleaved bf16 rows -------------
__global__ __launch_bounds__(256) void k_agg(
    const unsigned short* __restrict__ supb, const int* __restrict__ offsets,
    const int* __restrict__ ss, unsigned short* __restrict__ aggb, int nn)
{
    const int tid = threadIdx.x;
    const int lane = tid & 63;
    const int wv = tid >> 6;
    const int d = blockIdx.x * 4 + wv;
    if (d >= nn) return;
    const unsigned short* sp = supb + lane * 4;
    const int s0 = offsets[d], s1 = offsets[d + 1];
    float4 a = make_float4(0.f, 0.f, 0.f, 0.f);
    float4 a2 = make_float4(0.f, 0.f, 0.f, 0.f);
    int i = s0;
    for (; i + 4 <= s1; i += 4) {
        const int sA = ss[i], sB = ss[i + 1], sC = ss[i + 2], sD = ss[i + 3];
        const uint2 rA = *(const uint2*)(sp + (size_t)sA * 256);
        const uint2 rB = *(const uint2*)(sp + (size_t)sB * 256);
        const uint2 rC = *(const uint2*)(sp + (size_t)sC * 256);
        const uint2 rD = *(const uint2*)(sp + (size_t)sD * 256);
        a.x  += bf2f_lo(rA.x); a.y  += bf2f_hi(rA.x); a.z  += bf2f_lo(rA.y); a.w  += bf2f_hi(rA.y);
        a2.x += bf2f_lo(rB.x); a2.y += bf2f_hi(rB.x); a2.z += bf2f_lo(rB.y); a2.w += bf2f_hi(rB.y);
        a.x  += bf2f_lo(rC.x); a.y  += bf2f_hi(rC.x); a.z  += bf2f_lo(rC.y); a.w  += bf2f_hi(rC.y);
        a2.x += bf2f_lo(rD.x); a2.y += bf2f_hi(rD.x); a2.z += bf2f_lo(rD.y); a2.w += bf2f_hi(rD.y);
    }
    for (; i < s1; ++i) {
        const uint2 r = *(const uint2*)(sp + (size_t)ss[i] * 256);
        a.x += bf2f_lo(r.x); a.y += bf2f_hi(r.x); a.z += bf2f_lo(r.y); a.w += bf2f_hi(r.y);
    }
    a.x += a2.x; a.y += a2.y; a.z += a2.z; a.w += a2.w;
    ushort4 o;
    o.x = f2bf(a.x); o.y = f2bf(a.y); o.z = f2bf(a.z); o.w = f2bf(a.w);
    *(ushort4*)(aggb + (size_t)d * 256 + lane * 4) = o;
}

// ---------------- K3: gelu + MLP(128->64->32) + per-block h2 column sums ------
__global__ __launch_bounds__(512) void k_mlp(
    const unsigned short* __restrict__ aggb, const float* __restrict__ b0v,
    const float* __restrict__ W1, const float* __restrict__ b1v,
    const float* __restrict__ W2, const float* __restrict__ b2v,
    float* __restrict__ partials, int srows)
{
    __shared__ float w1s[HH][L1];
    __shared__ float w2s[L1][L2];
    __shared__ float hs[64 * 136];
    __shared__ float b0s[DD], b1s[L1], b2s[L2];
    __shared__ float oacc[64];

    const int tid = threadIdx.x;
    const int row0 = blockIdx.x * 64;

    for (int u = tid * 4; u < HH * L1; u += 2048)
        *(float4*)(&w1s[u >> 6][u & 63]) = *(const float4*)(W1 + u);
    for (int u = tid * 4; u < L1 * L2; u += 2048)
        *(float4*)(&w2s[u >> 5][u & 31]) = *(const float4*)(W2 + u);
    if (tid < DD) b0s[tid] = b0v[tid];
    if (tid < L1) b1s[tid] = b1v[tid];
    if (tid < L2) b2s[tid] = b2v[tid];
    if (tid < 64) oacc[tid] = 0.f;
    __syncthreads();

    for (int u = tid * 8; u < 64 * DD; u += 512 * 8) {
        const int r = u >> 7, c = u & 127;
        float4 g0 = make_float4(0.f, 0.f, 0.f, 0.f);
        float4 g1 = g0;
        if (row0 + r < srows) {
            const uint4 raw = *(const uint4*)(aggb + (size_t)(row0 + r) * HH + c);
            float v[8];
            v[0] = bf2f_lo(raw.x) + b0s[c + 0]; v[1] = bf2f_hi(raw.x) + b0s[c + 1];
            v[2] = bf2f_lo(raw.y) + b0s[c + 2]; v[3] = bf2f_hi(raw.y) + b0s[c + 3];
            v[4] = bf2f_lo(raw.z) + b0s[c + 4]; v[5] = bf2f_hi(raw.z) + b0s[c + 5];
            v[6] = bf2f_lo(raw.w) + b0s[c + 6]; v[7] = bf2f_hi(raw.w) + b0s[c + 7];
            #pragma unroll
            for (int t = 0; t < 8; ++t) v[t] = gelu_f(v[t]);
            g0 = make_float4(v[0], v[1], v[2], v[3]);
            g1 = make_float4(v[4], v[5], v[6], v[7]);
        }
        *(float4*)(&hs[r * 136 + c]) = g0;
        *(float4*)(&hs[r * 136 + c + 4]) = g1;
    }
    __syncthreads();

    const int cg = tid & 15;
    const int rg = tid >> 4;
    float4 acc0 = *(const float4*)(&b1s[cg * 4]);
    float4 acc1 = acc0;
    #pragma unroll 4
    for (int j = 0; j < HH; j += 4) {
        float4 wv[4];
        #pragma unroll
        for (int jj = 0; jj < 4; ++jj) wv[jj] = *(const float4*)(&w1s[j + jj][cg * 4]);
        const float4 h0 = *(const float4*)(&hs[(rg * 2 + 0) * 136 + j]);
        const float4 h1 = *(const float4*)(&hs[(rg * 2 + 1) * 136 + j]);
        acc0.x = fmaf(h0.x, wv[0].x, fmaf(h0.y, wv[1].x, fmaf(h0.z, wv[2].x, fmaf(h0.w, wv[3].x, acc0.x))));
        acc0.y = fmaf(h0.x, wv[0].y, fmaf(h0.y, wv[1].y, fmaf(h0.z, wv[2].y, fmaf(h0.w, wv[3].y, acc0.y))));
        acc0.z = fmaf(h0.x, wv[0].z, fmaf(h0.y, wv[1].z, fmaf(h0.z, wv[2].z, fmaf(h0.w, wv[3].z, acc0.z))));
        acc0.w = fmaf(h0.x, wv[0].w, fmaf(h0.y, wv[1].w, fmaf(h0.z, wv[2].w, fmaf(h0.w, wv[3].w, acc0.w))));
        acc1.x = fmaf(h1.x, wv[0].x, fmaf(h1.y, wv[1].x, fmaf(h1.z, wv[2].x, fmaf(h1.w, wv[3].x, acc1.x))));
        acc1.y = fmaf(h1.x, wv[0].y, fmaf(h1.y, wv[1].y, fmaf(h1.z, wv[2].y, fmaf(h1.w, wv[3].y, acc1.y))));
        acc1.z = fmaf(h1.x, wv[0].z, fmaf(h1.y, wv[1].z, fmaf(h1.z, wv[2].z, fmaf(h1.w, wv[3].z, acc1.z))));
        acc1.w = fmaf(h1.x, wv[0].w, fmaf(h1.y, wv[1].w, fmaf(h1.z, wv[2].w, fmaf(h1.w, wv[3].w, acc1.w))));
    }
    acc0.x = fmaxf(acc0.x, 0.f); acc0.y = fmaxf(acc0.y, 0.f);
    acc0.z = fmaxf(acc0.z, 0.f); acc0.w = fmaxf(acc0.w, 0.f);
    acc1.x = fmaxf(acc1.x, 0.f); acc1.y = fmaxf(acc1.y, 0.f);
    acc1.z = fmaxf(acc1.z, 0.f); acc1.w = fmaxf(acc1.w, 0.f);
    __syncthreads();
    float* h1p = hs;
    *(float4*)(&h1p[(rg * 2 + 0) * 68 + cg * 4]) = acc0;
    *(float4*)(&h1p[(rg * 2 + 1) * 68 + cg * 4]) = acc1;
    __syncthreads();

    float* h2p = hs + 5120;
    {
        const int cg2 = tid & 7;
        const int r2 = tid >> 3;
        float4 a = *(const float4*)(&b2s[cg2 * 4]);
        #pragma unroll 4
        for (int j = 0; j < L1; j += 4) {
            float4 wv[4];
            #pragma unroll
            for (int jj = 0; jj < 4; ++jj) wv[jj] = *(const float4*)(&w2s[j + jj][cg2 * 4]);
            const float4 hv = *(const float4*)(&h1p[r2 * 68 + j]);
            a.x = fmaf(hv.x, wv[0].x, fmaf(hv.y, wv[1].x, fmaf(hv.z, wv[2].x, fmaf(hv.w, wv[3].x, a.x))));
            a.y = fmaf(hv.x, wv[0].y, fmaf(hv.y, wv[1].y, fmaf(hv.z, wv[2].y, fmaf(hv.w, wv[3].y, a.y))));
            a.z = fmaf(hv.x, wv[0].z, fmaf(hv.y, wv[1].z, fmaf(hv.z, wv[2].z, fmaf(hv.w, wv[3].z, a.z))));
            a.w = fmaf(hv.x, wv[0].w, fmaf(hv.y, wv[1].w, fmaf(hv.z, wv[2].w, fmaf(hv.w, wv[3].w, a.w))));
        }
        a.x = fmaxf(a.x, 0.f); a.y = fmaxf(a.y, 0.f);
        a.z = fmaxf(a.z, 0.f); a.w = fmaxf(a.w, 0.f);
        __syncthreads();
        *(float4*)(&h2p[r2 * 36 + cg2 * 4]) = a;
    }
    __syncthreads();

    {
        const int c = tid & 31;
        const int g = tid >> 5;
        float p0 = 0.f, p1 = 0.f;
        #pragma unroll
        for (int i = 0; i < 4; ++i) {
            const int r = g * 4 + i;
            if (row0 + r < srows) {
                const float v = h2p[r * 36 + c];
                if (r & 1) p1 += v; else p0 += v;
            }
        }
        if (p0 != 0.f) atomicAdd(&oacc[c], p0);
        if (p1 != 0.f) atomicAdd(&oacc[32 + c], p1);
    }
    __syncthreads();
    if (tid < 64) partials[(size_t)blockIdx.x * 64 + tid] = oacc[tid];
}

// ---------------- Fallback path (ws too small for CSR) ----------------
__global__ __launch_bounds__(256) void k_scatter(
    const int* __restrict__ ei, const unsigned short* __restrict__ supb,
    float* __restrict__ aggf, int E)
{
    const int tid = threadIdx.x;
    const int eg = tid >> 6;
    const int lane = tid & 63;
    const int e = blockIdx.x * 4 + eg;
    if (e >= E) return;
    const int src = ei[e];
    const int dst = ei[E + e];
    const uint2 r = *(const uint2*)(supb + (size_t)src * 256 + lane * 4);
    float* ap = aggf + (size_t)dst * 256 + lane * 4;
    unsafeAtomicAdd(ap + 0, bf2f_lo(r.x));
    unsafeAtomicAdd(ap + 1, bf2f_hi(r.x));
    unsafeAtomicAdd(ap + 2, bf2f_lo(r.y));
    unsafeAtomicAdd(ap + 3, bf2f_hi(r.y));
}

__global__ __launch_bounds__(256) void k_cvt(
    const float* __restrict__ in, unsigned short* __restrict__ outb, int n)
{
    int i = blockIdx.x * 256 + threadIdx.x;
    if (i < n) outb[i] = f2bf(in[i]);
}

// ---------------- K4a: parallel reduce of partials ----------------
__global__ __launch_bounds__(256) void k_reduce(
    const float* __restrict__ partials, float* __restrict__ accum, int nblk)
{
    __shared__ float lsum[4][64];
    const int t = threadIdx.x & 63;
    const int w = threadIdx.x >> 6;
    float s = 0.f;
    for (int g = blockIdx.x * 4 + w; g < nblk; g += gridDim.x * 4)
        s += partials[(size_t)g * 64 + t];
    lsum[w][t] = s;
    __syncthreads();
    if (threadIdx.x < 64) {
        const float v = lsum[0][t] + lsum[1][t] + lsum[2][t] + lsum[3][t];
        unsafeAtomicAdd(&accum[t], v);
    }
}

// ---------------- K4b: apply layer3 to mean(h2) ----------------
__global__ __launch_bounds__(64) void k_final(
    const float* __restrict__ accum, const float* __restrict__ W3,
    const float* __restrict__ b3v, float* __restrict__ out)
{
    const int tid = threadIdx.x;
    if (tid < 2 * OO) {
        const int b = tid / OO, o = tid % OO;
        float acc = b3v[o];
        const float inv = 1.0f / (float)NN;
        #pragma unroll
        for (int j = 0; j < L2; ++j) acc += (accum[b * 32 + j] * inv) * W3[j * OO + o];
        out[tid] = acc;
    }
}

extern "C" void kernel_launch(void* const* d_in, const int* in_sizes, int n_in,
                              void* d_out, int out_size, void* d_ws, size_t ws_size,
                              hipStream_t stream) {
    const float* x  = (const float*)d_in[0];
    const int*   ei = (const int*)d_in[1];
    const float* W  = (const float*)d_in[2];
    const float* b0 = (const float*)d_in[3];
    const float* W1 = (const float*)d_in[4];
    const float* b1 = (const float*)d_in[5];
    const float* W2 = (const float*)d_in[6];
    const float* b2 = (const float*)d_in[7];
    const float* W3 = (const float*)d_in[8];
    const float* b3 = (const float*)d_in[9];
    float* out = (float*)d_out;

    const int E = in_sizes[1] / 2;           // 800000
    const int rows = 2 * NN;                 // 100000 storage rows
    const int nblk = (rows + 63) / 64;       // 1563
    const int nsb = (NN + 1023) / 1024;      // 49 scan blocks

    // workspace layout
    unsigned short* supb = (unsigned short*)d_ws;                    // rows*HH bf16 (interleaved)
    unsigned short* aggb = supb + (size_t)rows * HH;                 // rows*HH bf16 (interleaved)
    float* partials = (float*)(aggb + (size_t)rows * HH);            // nblk*64
    float* accum    = partials + (size_t)nblk * 64;                  // 64
    int*   counts   = (int*)(accum + 64);                            // NN
    int*   cursor   = counts + NN;                                   // NN
    int*   offsets  = cursor + NN;                                   // NN+1
    int*   blksum   = offsets + NN + 1;                              // 64
    unsigned short* wtb = (unsigned short*)(blksum + 64);            // 128*136 bf16
    int*   ss       = (int*)(wtb + 128 * 136);                       // E
    float* aggf     = (float*)(ss + E);                              // rows*HH (fallback only)
    const size_t need_csr = ((size_t)rows * HH * 2 + 128 * 136) * sizeof(unsigned short)
                      + ((size_t)nblk * 64 + 64) * sizeof(float)
                      + ((size_t)NN * 3 + 1 + 64 + E) * sizeof(int);
    const size_t need_fb = need_csr + (size_t)rows * HH * sizeof(float);

    if (ws_size >= need_csr && nsb <= 64) {
        hipMemsetAsync(accum, 0, (64 + 2 * (size_t)NN) * sizeof(int), stream);
        k_wprep<<<dim3((128 * 136 + 255) / 256), dim3(256), 0, stream>>>(W, wtb);
        k_support<<<dim3((rows + 63) / 64), dim3(256), 0, stream>>>(x, wtb, supb, rows, ei, counts, E);
        k_scan1<<<dim3(nsb), dim3(1024), 0, stream>>>(counts, offsets, blksum, NN);
        k_scan2<<<dim3(nsb), dim3(1024), 0, stream>>>(offsets, blksum, nsb, NN);
        k_bucket<<<dim3((E + 255) / 256), dim3(256), 0, stream>>>(ei, offsets, cursor, ss, E);
        k_agg<<<dim3((NN + 3) / 4), dim3(256), 0, stream>>>(supb, offsets, ss, aggb, NN);
        k_mlp<<<dim3(nblk), dim3(512), 0, stream>>>(aggb, b0, W1, b1, W2, b2, partials, rows);
    } else if (ws_size >= need_fb) {
        hipMemsetAsync(accum, 0, 64 * sizeof(float), stream);
        hipMemsetAsync(aggf, 0, (size_t)rows * HH * sizeof(float), stream);
        k_wprep<<<dim3((128 * 136 + 255) / 256), dim3(256), 0, stream>>>(W, wtb);
        k_support<<<dim3((rows + 63) / 64), dim3(256), 0, stream>>>(x, wtb, supb, rows, ei, counts, 0);
        k_scatter<<<dim3((E + 3) / 4), dim3(256), 0, stream>>>(ei, supb, aggf, E);
        k_cvt<<<dim3((rows * HH + 255) / 256), dim3(256), 0, stream>>>(aggf, aggb, rows * HH);
        k_mlp<<<dim3(nblk), dim3(512), 0, stream>>>(aggb, b0, W1, b1, W2, b2, partials, rows);
    }

    k_reduce<<<dim3(64), dim3(256), 0, stream>>>(partials, accum, nblk);
    k_final<<<dim3(1), dim3(64), 0, stream>>>(accum, W3, b3, out);
}

// Round 9
// 273.988 us; speedup vs baseline: 1.3268x; 1.1323x over previous
//
#include <hip/hip_runtime.h>
#include <math.h>

#define NN 50000
#define DD 128
#define HH 128
#define L1 64
#define L2 32
#define OO 10

typedef short v8s __attribute__((ext_vector_type(8)));   // 8 bf16 (4 VGPRs)
typedef float v4f __attribute__((ext_vector_type(4)));   // MFMA accumulator

// ---- bf16 helpers (manual: RNE pack) ----
__device__ __forceinline__ float bf2f_lo(unsigned u) { return __uint_as_float(u << 16); }
__device__ __forceinline__ float bf2f_hi(unsigned u) { return __uint_as_float(u & 0xffff0000u); }
__device__ __forceinline__ unsigned short f2bf(float f) {
    unsigned u = __float_as_uint(f);
    return (unsigned short)((u + 0x7fffu + ((u >> 16) & 1u)) >> 16);
}
__device__ __forceinline__ float gelu_f(float v) {
    return 0.5f * v * (1.f + erff(v * 0.70710678118654752f));
}

// ---------------- K0: transpose W, W1, W2 to bf16 B-operand layouts ----------
// wtb[128][136] = W^T; w1tb[64][136] = W1^T; w2tb[32][72] = W2^T (k-padded).
__global__ __launch_bounds__(256) void k_wprep(
    const float* __restrict__ W, const float* __restrict__ W1,
    const float* __restrict__ W2, unsigned short* __restrict__ wtb,
    unsigned short* __restrict__ w1tb, unsigned short* __restrict__ w2tb)
{
    int i = blockIdx.x * 256 + threadIdx.x;
    if (i < 128 * 136) {
        int n = i / 136, k = i % 136;
        wtb[i] = (k < DD) ? f2bf(W[k * HH + n]) : (unsigned short)0;
    } else if (i < 128 * 136 + 64 * 136) {
        int j = i - 128 * 136;
        int n = j / 136, k = j % 136;
        w1tb[j] = (k < HH) ? f2bf(W1[k * L1 + n]) : (unsigned short)0;
    } else if (i < 128 * 136 + 64 * 136 + 32 * 72) {
        int j = i - (128 * 136 + 64 * 136);
        int n = j / 72, k = j % 72;
        w2tb[j] = (k < L1) ? f2bf(W2[k * L2 + n]) : (unsigned short)0;
    }
}

// ---------------- K1: support = x @ W via bf16 MFMA + fused dst histogram ------
// 128 rows/block, 512 threads (8 waves); wave w -> rows w*16..+16, 8 col-tiles.
// LDS: xs 128x136 bf16 + wt 128x136 bf16 = 70 KB -> 2 blk/CU, 16 waves/CU.
// Output interleaved: storage row = node*2+batch.
__global__ __launch_bounds__(512, 4) void k_support(
    const float* __restrict__ x, const unsigned short* __restrict__ wtb,
    unsigned short* __restrict__ supb, int rows,
    const int* __restrict__ ei, int* __restrict__ counts, int E)
{
    __shared__ __align__(16) unsigned short xs[128 * 136];
    __shared__ __align__(16) unsigned short wt[128 * 136];
    const int tid = threadIdx.x;
    const int row0 = blockIdx.x * 128;

    for (int u = tid * 4; u < 128 * 136; u += 2048)
        *(uint2*)(&wt[u]) = *(const uint2*)(wtb + u);
    for (int u = tid * 4; u < 128 * DD; u += 2048) {
        const int r = u >> 7, c = u & 127;
        float4 v = make_float4(0.f, 0.f, 0.f, 0.f);
        if (row0 + r < rows) v = *(const float4*)(x + (size_t)(row0 + r) * DD + c);
        ushort4 o;
        o.x = f2bf(v.x); o.y = f2bf(v.y); o.z = f2bf(v.z); o.w = f2bf(v.w);
        *(ushort4*)(&xs[r * 136 + c]) = o;
    }

    // fused dst-histogram (independent; hides under staging/MFMA)
    {
        const int chunk = (E + gridDim.x - 1) / gridDim.x;
        const int e0 = blockIdx.x * chunk;
        const int e1 = min(e0 + chunk, E);
        for (int e = e0 + tid; e < e1; e += 512)
            atomicAdd(&counts[ei[(size_t)E + e]], 1);
    }
    __syncthreads();

    const int lane = tid & 63;
    const int w = tid >> 6;       // wave 0..7
    const int m0 = w * 16;        // wave's row base (block-local)
    const int lm = lane & 15;
    const int q  = lane >> 4;     // 0..3

    v4f acc[8];
    #pragma unroll
    for (int i = 0; i < 8; ++i) acc[i] = (v4f)(0.f);

    #pragma unroll
    for (int ks = 0; ks < 4; ++ks) {
        const int k0 = ks * 32 + q * 8;
        const v8s af = *(const v8s*)(&xs[(m0 + lm) * 136 + k0]);
        #pragma unroll
        for (int ct = 0; ct < 8; ++ct) {
            const v8s bf = *(const v8s*)(&wt[(ct * 16 + lm) * 136 + k0]);
            acc[ct] = __builtin_amdgcn_mfma_f32_16x16x32_bf16(af, bf, acc[ct], 0, 0, 0);
        }
    }

    // C/D: col = ct*16 + lm, row = q*4 + reg  [m89-verified]
    #pragma unroll
    for (int ct = 0; ct < 8; ++ct) {
        const int col = ct * 16 + lm;
        #pragma unroll
        for (int r = 0; r < 4; ++r) {
            const int rowg = row0 + m0 + q * 4 + r;
            if (rowg < rows) {
                const int b = (rowg >= NN) ? 1 : 0;
                const int n = rowg - b * NN;
                supb[((size_t)n * 2 + b) * HH + col] = f2bf(acc[ct][r]);
            }
        }
    }
}

// ---------------- multi-block scan, stage 1 ----------------
__global__ __launch_bounds__(1024) void k_scan1(
    const int* __restrict__ counts, int* __restrict__ offsets,
    int* __restrict__ blksum, int n)
{
    __shared__ int wsum[16], woff[16];
    const int tid = threadIdx.x, lane = tid & 63, wv = tid >> 6;
    const int i = blockIdx.x * 1024 + tid;
    int v = (i < n) ? counts[i] : 0;
    int x = v;
    #pragma unroll
    for (int d = 1; d < 64; d <<= 1) { int t = __shfl_up(x, d); if (lane >= d) x += t; }
    if (lane == 63) wsum[wv] = x;
    __syncthreads();
    if (wv == 0 && lane < 16) {
        int y = wsum[lane];
        #pragma unroll
        for (int d = 1; d < 16; d <<= 1) { int t = __shfl_up(y, d); if (lane >= d) y += t; }
        woff[lane] = y - wsum[lane];
        if (lane == 15) blksum[blockIdx.x] = y;
    }
    __syncthreads();
    if (i < n) offsets[i] = woff[wv] + (x - v);
}

// ---------------- multi-block scan, stage 2 ----------------
__global__ __launch_bounds__(1024) void k_scan2(
    int* __restrict__ offsets, const int* __restrict__ blksum, int nblk, int n)
{
    __shared__ int base_sh, tot_sh;
    const int tid = threadIdx.x, lane = tid & 63, wv = tid >> 6;
    if (wv == 0) {
        int v = (lane < nblk) ? blksum[lane] : 0;
        int x = v;
        #pragma unroll
        for (int d = 1; d < 64; d <<= 1) { int t = __shfl_up(x, d); if (lane >= d) x += t; }
        int incl = __shfl(x, blockIdx.x);
        int own  = __shfl(v, blockIdx.x);
        int tot  = __shfl(x, nblk - 1);
        if (lane == 0) { base_sh = incl - own; tot_sh = tot; }
    }
    __syncthreads();
    const int i = blockIdx.x * 1024 + tid;
    if (i < n) offsets[i] += base_sh;
    if (blockIdx.x == nblk - 1 && tid == 0) offsets[n] = tot_sh;
}

// ---------------- CSR build: bucket src indices by dst ----------------
__global__ __launch_bounds__(256) void k_bucket(
    const int* __restrict__ ei, const int* __restrict__ offsets,
    int* __restrict__ cursor, int* __restrict__ ss, int E)
{
    int e = blockIdx.x * 256 + threadIdx.x;
    if (e < E) {
        int d = ei[E + e];
        int pos = offsets[d] + atomicAdd(&cursor[d], 1);
        ss[pos] = ei[e];
    }
}

// ---------------- K2: gather-aggregate over interleaved bf16 rows -------------
__global__ __launch_bounds__(256) void k_agg(
    const unsigned short* __restrict__ supb, const int* __restrict__ offsets,
    const int* __restrict__ ss, unsigned short* __restrict__ aggb, int nn)
{
    const int tid = threadIdx.x;
    const int lane = tid & 63;
    const int wv = tid >> 6;
    const int d = blockIdx.x * 4 + wv;
    if (d >= nn) return;
    const unsigned short* sp = supb + lane * 4;
    const int s0 = offsets[d], s1 = offsets[d + 1];
    float4 a = make_float4(0.f, 0.f, 0.f, 0.f);
    float4 a2 = make_float4(0.f, 0.f, 0.f, 0.f);
    int i = s0;
    for (; i + 4 <= s1; i += 4) {
        const int sA = ss[i], sB = ss[i + 1], sC = ss[i + 2], sD = ss[i + 3];
        const uint2 rA = *(const uint2*)(sp + (size_t)sA * 256);
        const uint2 rB = *(const uint2*)(sp + (size_t)sB * 256);
        const uint2 rC = *(const uint2*)(sp + (size_t)sC * 256);
        const uint2 rD = *(const uint2*)(sp + (size_t)sD * 256);
        a.x  += bf2f_lo(rA.x); a.y  += bf2f_hi(rA.x); a.z  += bf2f_lo(rA.y); a.w  += bf2f_hi(rA.y);
        a2.x += bf2f_lo(rB.x); a2.y += bf2f_hi(rB.x); a2.z += bf2f_lo(rB.y); a2.w += bf2f_hi(rB.y);
        a.x  += bf2f_lo(rC.x); a.y  += bf2f_hi(rC.x); a.z  += bf2f_lo(rC.y); a.w  += bf2f_hi(rC.y);
        a2.x += bf2f_lo(rD.x); a2.y += bf2f_hi(rD.x); a2.z += bf2f_lo(rD.y); a2.w += bf2f_hi(rD.y);
    }
    for (; i < s1; ++i) {
        const uint2 r = *(const uint2*)(sp + (size_t)ss[i] * 256);
        a.x += bf2f_lo(r.x); a.y += bf2f_hi(r.x); a.z += bf2f_lo(r.y); a.w += bf2f_hi(r.y);
    }
    a.x += a2.x; a.y += a2.y; a.z += a2.z; a.w += a2.w;
    ushort4 o;
    o.x = f2bf(a.x); o.y = f2bf(a.y); o.z = f2bf(a.z); o.w = f2bf(a.w);
    *(ushort4*)(aggb + (size_t)d * 256 + lane * 4) = o;
}

// ---------------- K3: gelu + MFMA MLP(128->64->32) + column sums --------------
// 64 storage rows/block, 512 threads (8 waves). All matmuls on matrix cores.
// LDS ~50 KB (h2p overlays dead hsb) -> 3 blocks/CU, 24 waves/CU.
__global__ __launch_bounds__(512, 6) void k_mlp(
    const unsigned short* __restrict__ aggb, const float* __restrict__ b0v,
    const unsigned short* __restrict__ w1tb, const float* __restrict__ b1v,
    const unsigned short* __restrict__ w2tb, const float* __restrict__ b2v,
    float* __restrict__ partials, int srows)
{
    __shared__ __align__(16) unsigned short wt1[64 * 136];      // 17.4 KB
    __shared__ __align__(16) unsigned short wt2[32 * 72];       // 4.6 KB
    __shared__ __align__(16) unsigned char upool[64 * 136 * 2]; // hsb bf16 / h2p f32
    __shared__ __align__(16) unsigned short h1b[64 * 72];       // 9.2 KB
    __shared__ float b0s[DD], b1s[L1], b2s[L2];
    __shared__ float oacc[64];
    unsigned short* hsb = (unsigned short*)upool;   // [64][136] bf16
    float* h2p = (float*)upool;                     // [64][36] f32 (after hsb dead)

    const int tid = threadIdx.x;
    const int row0 = blockIdx.x * 64;

    for (int u = tid * 4; u < 64 * 136; u += 2048)
        *(uint2*)(&wt1[u]) = *(const uint2*)(w1tb + u);
    for (int u = tid * 4; u < 32 * 72; u += 2048)
        *(uint2*)(&wt2[u]) = *(const uint2*)(w2tb + u);
    if (tid < DD) b0s[tid] = b0v[tid];
    if (tid < L1) b1s[tid] = b1v[tid];
    if (tid < L2) b2s[tid] = b2v[tid];
    if (tid < 64) oacc[tid] = 0.f;

    // gelu(agg + b0) -> hsb (bf16, A-operand layout = row-major padded)
    for (int u = tid * 8; u < 64 * DD; u += 4096) {
        const int r = u >> 7, c = u & 127;
        uint4 raw = make_uint4(0, 0, 0, 0);
        if (row0 + r < srows) raw = *(const uint4*)(aggb + (size_t)(row0 + r) * HH + c);
        float v[8];
        v[0] = bf2f_lo(raw.x) + b0s[c + 0]; v[1] = bf2f_hi(raw.x) + b0s[c + 1];
        v[2] = bf2f_lo(raw.y) + b0s[c + 2]; v[3] = bf2f_hi(raw.y) + b0s[c + 3];
        v[4] = bf2f_lo(raw.z) + b0s[c + 4]; v[5] = bf2f_hi(raw.z) + b0s[c + 5];
        v[6] = bf2f_lo(raw.w) + b0s[c + 6]; v[7] = bf2f_hi(raw.w) + b0s[c + 7];
        ushort4 o0, o1;
        o0.x = f2bf(gelu_f(v[0])); o0.y = f2bf(gelu_f(v[1]));
        o0.z = f2bf(gelu_f(v[2])); o0.w = f2bf(gelu_f(v[3]));
        o1.x = f2bf(gelu_f(v[4])); o1.y = f2bf(gelu_f(v[5]));
        o1.z = f2bf(gelu_f(v[6])); o1.w = f2bf(gelu_f(v[7]));
        *(ushort4*)(&hsb[r * 136 + c]) = o0;
        *(ushort4*)(&hsb[r * 136 + c + 4]) = o1;
    }
    __syncthreads();

    const int lane = tid & 63;
    const int w = tid >> 6;       // 0..7
    const int lm = lane & 15;
    const int q = lane >> 4;
    const int r1 = (w & 3) * 16;  // row-tile base

    // layer1 (64x128 @ 128x64): wave w -> rows r1..+16, cols (w>>2)*32..+32
    {
        const int c1 = (w >> 2) * 32;
        v4f a1[2];
        a1[0] = (v4f)(0.f); a1[1] = (v4f)(0.f);
        #pragma unroll
        for (int ks = 0; ks < 4; ++ks) {
            const int k0 = ks * 32 + q * 8;
            const v8s af = *(const v8s*)(&hsb[(r1 + lm) * 136 + k0]);
            #pragma unroll
            for (int ct = 0; ct < 2; ++ct) {
                const v8s bf = *(const v8s*)(&wt1[(c1 + ct * 16 + lm) * 136 + k0]);
                a1[ct] = __builtin_amdgcn_mfma_f32_16x16x32_bf16(af, bf, a1[ct], 0, 0, 0);
            }
        }
        #pragma unroll
        for (int ct = 0; ct < 2; ++ct) {
            const int col = c1 + ct * 16 + lm;
            const float bias = b1s[col];
            #pragma unroll
            for (int r = 0; r < 4; ++r)
                h1b[(r1 + q * 4 + r) * 72 + col] = f2bf(fmaxf(a1[ct][r] + bias, 0.f));
        }
    }
    __syncthreads();

    // layer2 (64x64 @ 64x32): wave w -> rows r1..+16, cols (w>>2)*16..+16
    {
        const int c2 = (w >> 2) * 16;
        v4f a2 = (v4f)(0.f);
        #pragma unroll
        for (int ks = 0; ks < 2; ++ks) {
            const int k0 = ks * 32 + q * 8;
            const v8s af = *(const v8s*)(&h1b[(r1 + lm) * 72 + k0]);
            const v8s bf = *(const v8s*)(&wt2[(c2 + lm) * 72 + k0]);
            a2 = __builtin_amdgcn_mfma_f32_16x16x32_bf16(af, bf, a2, 0, 0, 0);
        }
        const int col = c2 + lm;
        const float bias = b2s[col];
        #pragma unroll
        for (int r = 0; r < 4; ++r)
            h2p[(r1 + q * 4 + r) * 36 + col] = fmaxf(a2[r] + bias, 0.f);
    }
    __syncthreads();

    // column sums: storage row r -> batch r&1
    {
        const int c = tid & 31;
        const int g = tid >> 5;   // 0..15, 4 rows each
        float p0 = 0.f, p1 = 0.f;
        #pragma unroll
        for (int i = 0; i < 4; ++i) {
            const int r = g * 4 + i;
            if (row0 + r < srows) {
                const float v = h2p[r * 36 + c];
                if (r & 1) p1 += v; else p0 += v;
            }
        }
        if (p0 != 0.f) atomicAdd(&oacc[c], p0);
        if (p1 != 0.f) atomicAdd(&oacc[32 + c], p1);
    }
    __syncthreads();
    if (tid < 64) partials[(size_t)blockIdx.x * 64 + tid] = oacc[tid];
}

// ---------------- Fallback path (ws too small for CSR) ----------------
__global__ __launch_bounds__(256) void k_scatter(
    const int* __restrict__ ei, const unsigned short* __restrict__ supb,
    float* __restrict__ aggf, int E)
{
    const int tid = threadIdx.x;
    const int eg = tid >> 6;
    const int lane = tid & 63;
    const int e = blockIdx.x * 4 + eg;
    if (e >= E) return;
    const int src = ei[e];
    const int dst = ei[E + e];
    const uint2 r = *(const uint2*)(supb + (size_t)src * 256 + lane * 4);
    float* ap = aggf + (size_t)dst * 256 + lane * 4;
    unsafeAtomicAdd(ap + 0, bf2f_lo(r.x));
    unsafeAtomicAdd(ap + 1, bf2f_hi(r.x));
    unsafeAtomicAdd(ap + 2, bf2f_lo(r.y));
    unsafeAtomicAdd(ap + 3, bf2f_hi(r.y));
}

__global__ __launch_bounds__(256) void k_cvt(
    const float* __restrict__ in, unsigned short* __restrict__ outb, int n)
{
    int i = blockIdx.x * 256 + threadIdx.x;
    if (i < n) outb[i] = f2bf(in[i]);
}

// ---------------- K4a: parallel reduce of partials ----------------
__global__ __launch_bounds__(256) void k_reduce(
    const float* __restrict__ partials, float* __restrict__ accum, int nblk)
{
    __shared__ float lsum[4][64];
    const int t = threadIdx.x & 63;
    const int w = threadIdx.x >> 6;
    float s = 0.f;
    for (int g = blockIdx.x * 4 + w; g < nblk; g += gridDim.x * 4)
        s += partials[(size_t)g * 64 + t];
    lsum[w][t] = s;
    __syncthreads();
    if (threadIdx.x < 64) {
        const float v = lsum[0][t] + lsum[1][t] + lsum[2][t] + lsum[3][t];
        unsafeAtomicAdd(&accum[t], v);
    }
}

// ---------------- K4b: apply layer3 to mean(h2) ----------------
__global__ __launch_bounds__(64) void k_final(
    const float* __restrict__ accum, const float* __restrict__ W3,
    const float* __restrict__ b3v, float* __restrict__ out)
{
    const int tid = threadIdx.x;
    if (tid < 2 * OO) {
        const int b = tid / OO, o = tid % OO;
        float acc = b3v[o];
        const float inv = 1.0f / (float)NN;
        #pragma unroll
        for (int j = 0; j < L2; ++j) acc += (accum[b * 32 + j] * inv) * W3[j * OO + o];
        out[tid] = acc;
    }
}

extern "C" void kernel_launch(void* const* d_in, const int* in_sizes, int n_in,
                              void* d_out, int out_size, void* d_ws, size_t ws_size,
                              hipStream_t stream) {
    const float* x  = (const float*)d_in[0];
    const int*   ei = (const int*)d_in[1];
    const float* W  = (const float*)d_in[2];
    const float* b0 = (const float*)d_in[3];
    const float* W1 = (const float*)d_in[4];
    const float* b1 = (const float*)d_in[5];
    const float* W2 = (const float*)d_in[6];
    const float* b2 = (const float*)d_in[7];
    const float* W3 = (const float*)d_in[8];
    const float* b3 = (const float*)d_in[9];
    float* out = (float*)d_out;

    const int E = in_sizes[1] / 2;           // 800000
    const int rows = 2 * NN;                 // 100000 storage rows
    const int nblk = (rows + 63) / 64;       // 1563 (mlp blocks)
    const int nsb = (NN + 1023) / 1024;      // 49 scan blocks
    const int wpn = 128 * 136 + 64 * 136 + 32 * 72;   // 28416 prep elements

    // workspace layout
    unsigned short* supb = (unsigned short*)d_ws;                    // rows*HH bf16 (interleaved)
    unsigned short* aggb = supb + (size_t)rows * HH;                 // rows*HH bf16 (interleaved)
    float* partials = (float*)(aggb + (size_t)rows * HH);            // nblk*64
    float* accum    = partials + (size_t)nblk * 64;                  // 64
    int*   counts   = (int*)(accum + 64);                            // NN
    int*   cursor   = counts + NN;                                   // NN
    int*   offsets  = cursor + NN;                                   // NN+1
    int*   blksum   = offsets + NN + 1;                              // 64
    unsigned short* wtb  = (unsigned short*)(blksum + 64);           // 128*136
    unsigned short* w1tb = wtb + 128 * 136;                          // 64*136
    unsigned short* w2tb = w1tb + 64 * 136;                          // 32*72
    int*   ss       = (int*)(w2tb + 32 * 72);                        // E
    float* aggf     = (float*)(ss + E);                              // rows*HH (fallback only)
    const size_t need_csr = ((size_t)rows * HH * 2 + wpn) * sizeof(unsigned short)
                      + ((size_t)nblk * 64 + 64) * sizeof(float)
                      + ((size_t)NN * 3 + 1 + 64 + E) * sizeof(int);
    const size_t need_fb = need_csr + (size_t)rows * HH * sizeof(float);

    if (ws_size >= need_csr && nsb <= 64) {
        hipMemsetAsync(accum, 0, (64 + 2 * (size_t)NN) * sizeof(int), stream);
        k_wprep<<<dim3((wpn + 255) / 256), dim3(256), 0, stream>>>(W, W1, W2, wtb, w1tb, w2tb);
        k_support<<<dim3((rows + 127) / 128), dim3(512), 0, stream>>>(x, wtb, supb, rows, ei, counts, E);
        k_scan1<<<dim3(nsb), dim3(1024), 0, stream>>>(counts, offsets, blksum, NN);
        k_scan2<<<dim3(nsb), dim3(1024), 0, stream>>>(offsets, blksum, nsb, NN);
        k_bucket<<<dim3((E + 255) / 256), dim3(256), 0, stream>>>(ei, offsets, cursor, ss, E);
        k_agg<<<dim3((NN + 3) / 4), dim3(256), 0, stream>>>(supb, offsets, ss, aggb, NN);
        k_mlp<<<dim3(nblk), dim3(512), 0, stream>>>(aggb, b0, w1tb, b1, w2tb, b2, partials, rows);
    } else if (ws_size >= need_fb) {
        hipMemsetAsync(accum, 0, 64 * sizeof(float), stream);
        hipMemsetAsync(aggf, 0, (size_t)rows * HH * sizeof(float), stream);
        k_wprep<<<dim3((wpn + 255) / 256), dim3(256), 0, stream>>>(W, W1, W2, wtb, w1tb, w2tb);
        k_support<<<dim3((rows + 127) / 128), dim3(512), 0, stream>>>(x, wtb, supb, rows, ei, counts, 0);
        k_scatter<<<dim3((E + 3) / 4), dim3(256), 0, stream>>>(ei, supb, aggf, E);
        k_cvt<<<dim3((rows * HH + 255) / 256), dim3(256), 0, stream>>>(aggf, aggb, rows * HH);
        k_mlp<<<dim3(nblk), dim3(512), 0, stream>>>(aggb, b0, w1tb, b1, w2tb, b2, partials, rows);
    }

    k_reduce<<<dim3(64), dim3(256), 0, stream>>>(partials, accum, nblk);
    k_final<<<dim3(1), dim3(64), 0, stream>>>(accum, W3, b3, out);
}